// Round 6
// baseline (535.176 us; speedup 1.0000x reference)
//
#include <hip/hip_runtime.h>

#define Bc 4
#define Lc 4096
#define Dc 1024
#define LDQ 3072
#define Mc (Bc*Lc)
#define EPSc 1e-6f

typedef __bf16 bf16x8 __attribute__((ext_vector_type(8)));
typedef __bf16 bf16x4 __attribute__((ext_vector_type(4)));
typedef float f32x4 __attribute__((ext_vector_type(4)));

typedef __attribute__((address_space(3))) void lds_vt;
typedef const __attribute__((address_space(1))) void gbl_vt;

__device__ __forceinline__ void gll16(const void* g, void* l) {
  __builtin_amdgcn_global_load_lds((gbl_vt*)g, (lds_vt*)l, 16, 0, 0);
}

// ---------------- converts ----------------
__global__ __launch_bounds__(256) void conv_bf16(const float* __restrict__ X, __bf16* __restrict__ Y) {
  const int i = blockIdx.x * 256 + threadIdx.x;
  const float4 v = ((const float4*)X)[i];
  bf16x4 o;
  o[0] = (__bf16)v.x; o[1] = (__bf16)v.y; o[2] = (__bf16)v.z; o[3] = (__bf16)v.w;
  ((bf16x4*)Y)[i] = o;
}

__global__ __launch_bounds__(256) void wt_conv(const float* __restrict__ W, __bf16* __restrict__ Wt) {
  __shared__ float t[32][33];
  const int n0 = blockIdx.x << 5, k0 = blockIdx.y << 5;
  const int tx = threadIdx.x, ty = threadIdx.y;  // block (32,8)
#pragma unroll
  for (int i = 0; i < 4; ++i)
    t[ty + 8 * i][tx] = W[(size_t)(k0 + ty + 8 * i) * Dc + n0 + tx];
  __syncthreads();
#pragma unroll
  for (int i = 0; i < 4; ++i)
    Wt[(size_t)(n0 + ty + 8 * i) * Dc + k0 + tx] = (__bf16)t[tx][ty + 8 * i];
}

// ---------------- GEMM 256x256, BK=64, 8-phase schedule (m201 port) ----------------
// 2 K-tiles/iteration, 8 phases; each phase: {ds-read subtile || stage 1 half-tile
// (2 gll16/thread) -> barrier -> lgkmcnt(0)+sched_barrier -> setprio(1) 16 MFMA
// setprio(0) -> [vmcnt(4) at P3/P7] -> barrier}. Stage slots: P2=b0.A0 P3=b0.A1
// P4=b0.B0 P5=b0.B1 P6=b1.A0 P7=b1.A1 P0=b1.B0 P1=b1.B1 (race-free: each region
// staged after its last read-phase; each read covered by a prior vmcnt+barrier).
// FUSED=1: grouped QKV projection (sigmoid Q,K; col-sum atomics; bf16 out ld=3072).
// FUSED=0: plain C = A@Wt^T + bias, fp32 out ld=1024.
// MFMA operands swapped (mfma(B,A)) so each lane holds 4 consecutive out-cols.
template <int FUSED>
__global__ __launch_bounds__(512, 2) void gemm256(
    const __bf16* __restrict__ Aq_, const __bf16* __restrict__ Ak_, const __bf16* __restrict__ Av_,
    const __bf16* __restrict__ Wq_, const __bf16* __restrict__ Wk_, const __bf16* __restrict__ Wv_,
    const float* __restrict__ bq_, const float* __restrict__ bk_, const float* __restrict__ bv_,
    void* __restrict__ Cp, float* __restrict__ qsum, float* __restrict__ ksum) {
  __shared__ __bf16 As[2][16384];
  __shared__ __bf16 Bs[2][16384];
  const int tid = threadIdx.x;
  const int lane = tid & 63, w8 = tid >> 6;
  const int wr = w8 >> 2, wc = w8 & 3;          // 2 x 4 waves
  const int lf = lane & 15, kq = lane >> 4;

  // XCD-chunked bijective swizzle; cols fastest within a chunk (A-panel reuse per XCD)
  constexpr int NBY = FUSED ? 12 : 4;
  constexpr int CPX = (64 * NBY) >> 3;
  const int hwlin = blockIdx.x + (blockIdx.y << 6);
  const int swz = (hwlin & 7) * CPX + (hwlin >> 3);
  const int bx = swz / NBY, by = swz - bx * NBY;
  const int row0 = bx << 8, col0 = by << 8;
  const int region = FUSED ? (col0 >> 10) : 0;
  const int colL = FUSED ? (col0 & 1023) : col0;

  const __bf16* Agl = FUSED ? (region == 0 ? Aq_ : (region == 1 ? Ak_ : Av_)) : Aq_;
  const __bf16* Bgl = FUSED ? (region == 0 ? Wq_ : (region == 1 ? Wk_ : Wv_)) : Wq_;
  const float* biasp = FUSED ? (region == 0 ? bq_ : (region == 1 ? bk_ : bv_)) : bq_;
  const __bf16* Ab_g = Agl + (size_t)row0 * 1024;
  const __bf16* Bb_g = Bgl + (size_t)colL * 1024;

  // fragment read bases (element offsets); swizzled 8-elem k-granules
  const int abase = (wr * 128 + lf) * 64;
  const int bbase = (wc * 64 + lf) * 64;
  const int kg0 = (kq ^ (lf & 7)) << 3;
  const int kg1 = ((4 + kq) ^ (lf & 7)) << 3;

  // Stage ONE half-tile (128 rows x 64 k = 16KB): 2 gll16/thread. OP: 0=A 1=B.
  // granule g = i*512+tid -> rowInHalf = g>>3, kg = g&7; LDS linear, source pre-swizzled.
#define STG_H(OP, HALF, TK, BUF) do { \
    _Pragma("unroll") \
    for (int i_ = 0; i_ < 2; ++i_) { \
      const int g_ = i_ * 512 + tid; \
      const int r_ = g_ >> 3, kg_ = g_ & 7; \
      const int gr_ = ((HALF) << 7) + r_; \
      if ((OP) == 0) \
        gll16(Ab_g + (size_t)gr_ * 1024 + ((TK) << 6) + ((kg_ ^ (r_ & 7)) << 3), \
              &As[BUF][((HALF) << 13) + r_ * 64 + (kg_ << 3)]); \
      else \
        gll16(Bb_g + (size_t)gr_ * 1024 + ((TK) << 6) + ((kg_ ^ (r_ & 7)) << 3), \
              &Bs[BUF][((HALF) << 13) + r_ * 64 + (kg_ << 3)]); \
    } \
  } while (0)

#define RDA(DST, BUF, MB) _Pragma("unroll") for (int m_ = 0; m_ < 4; ++m_) { \
    DST[m_][0] = *(const bf16x8*)(&As[BUF][0] + abase + ((MB) + m_) * 1024 + kg0); \
    DST[m_][1] = *(const bf16x8*)(&As[BUF][0] + abase + ((MB) + m_) * 1024 + kg1); }
#define RDB(DST, BUF, NB) _Pragma("unroll") for (int n_ = 0; n_ < 2; ++n_) { \
    DST[n_][0] = *(const bf16x8*)(&Bs[BUF][0] + bbase + ((NB) + n_) * 1024 + kg0); \
    DST[n_][1] = *(const bf16x8*)(&Bs[BUF][0] + bbase + ((NB) + n_) * 1024 + kg1); }
#define MM(MB, NB, AFR, BFR) _Pragma("unroll") for (int m_ = 0; m_ < 4; ++m_) \
    _Pragma("unroll") for (int n_ = 0; n_ < 2; ++n_) \
    _Pragma("unroll") for (int k_ = 0; k_ < 2; ++k_) \
      acc[(MB) + m_][(NB) + n_] = __builtin_amdgcn_mfma_f32_16x16x32_bf16( \
          BFR[n_][k_], AFR[m_][k_], acc[(MB) + m_][(NB) + n_], 0, 0, 0);
#define BARx asm volatile("s_barrier" ::: "memory")
#define LGKM0 do { asm volatile("s_waitcnt lgkmcnt(0)" ::: "memory"); \
                   __builtin_amdgcn_sched_barrier(0); } while (0)
#define PRIO1 __builtin_amdgcn_s_setprio(1);
#define PRIO0 __builtin_amdgcn_s_setprio(0);

  f32x4 acc[8][4] = {};

  // prologue: tile0 (A+B) -> buf0, tile1 A-halves -> buf1
  STG_H(0, 0, 0, 0); STG_H(0, 1, 0, 0);
  STG_H(1, 0, 0, 0); STG_H(1, 1, 0, 0);
  STG_H(0, 0, 1, 1); STG_H(0, 1, 1, 1);
  asm volatile("s_waitcnt vmcnt(4)" ::: "memory");   // tile0 fully landed
  BARx;

  for (int it = 0; it < 8; ++it) {
    const int t1 = 2 * it + 1;
    const bool pre = it < 7;
    bf16x8 af0[4][2], af1[4][2], bf0[2][2], bf1[2][2];
    // ---- tile 2it (buf0) ----
    // P0: reads af0+bf0; stage buf1.B-H0 (tile t1)
    RDA(af0, 0, 0) RDB(bf0, 0, 0)
    STG_H(1, 0, t1, 1);
    BARx; LGKM0;
    PRIO1 MM(0, 0, af0, bf0) PRIO0
    BARx;
    // P1: reads af1; stage buf1.B-H1
    RDA(af1, 0, 4)
    STG_H(1, 1, t1, 1);
    BARx; LGKM0;
    PRIO1 MM(4, 0, af1, bf0) PRIO0
    BARx;
    // P2: reads bf1; stage buf0.A-H0 (tile 2it+2)
    RDB(bf1, 0, 2)
    if (pre) STG_H(0, 0, t1 + 1, 0);
    BARx; LGKM0;
    PRIO1 MM(0, 2, af0, bf1) PRIO0
    BARx;
    // P3: stage buf0.A-H1; counted drain
    if (pre) STG_H(0, 1, t1 + 1, 0);
    BARx;
    PRIO1 MM(4, 2, af1, bf1) PRIO0
    if (pre) asm volatile("s_waitcnt vmcnt(4)" ::: "memory");
    else     asm volatile("s_waitcnt vmcnt(0)" ::: "memory");
    BARx;
    // ---- tile 2it+1 (buf1) ----
    // P4: reads af0+bf0; stage buf0.B-H0
    RDA(af0, 1, 0) RDB(bf0, 1, 0)
    if (pre) STG_H(1, 0, t1 + 1, 0);
    BARx; LGKM0;
    PRIO1 MM(0, 0, af0, bf0) PRIO0
    BARx;
    // P5: reads af1; stage buf0.B-H1
    RDA(af1, 1, 4)
    if (pre) STG_H(1, 1, t1 + 1, 0);
    BARx; LGKM0;
    PRIO1 MM(4, 0, af1, bf0) PRIO0
    BARx;
    // P6: reads bf1; stage buf1.A-H0 (tile t1+2)
    RDB(bf1, 1, 2)
    if (pre) STG_H(0, 0, t1 + 2, 1);
    BARx; LGKM0;
    PRIO1 MM(0, 2, af0, bf1) PRIO0
    BARx;
    // P7: stage buf1.A-H1; counted drain
    if (pre) STG_H(0, 1, t1 + 2, 1);
    BARx;
    PRIO1 MM(4, 2, af1, bf1) PRIO0
    if (pre) asm volatile("s_waitcnt vmcnt(4)" ::: "memory");
    BARx;
  }
#undef STG_H
#undef RDA
#undef RDB
#undef MM

  // epilogue (transposed acc): lane -> row = row0+wr*128+lf+mi*16,
  // cols = col0+wc*64+ni*16+kq*4 + (0..3) contiguous -> wide stores.
  const int b_of = row0 >> 12;
  const int orow = row0 + wr * 128 + lf;
  const int ocl = wc * 64 + (kq << 2);
#pragma unroll
  for (int ni = 0; ni < 4; ++ni) {
    const int cl = ocl + (ni << 4);          // 0..255 within tile
    const int cb = colL + cl;                // 0..1023 bias/sum col
    const f32x4 bb = *(const f32x4*)&biasp[cb];
    f32x4 sacc = {0.f, 0.f, 0.f, 0.f};
#pragma unroll
    for (int mi = 0; mi < 8; ++mi) {
      f32x4 v = acc[mi][ni] + bb;
      if (FUSED && region < 2) {
#pragma unroll
        for (int r = 0; r < 4; ++r) v[r] = 1.0f / (1.0f + expf(-v[r]));
      }
      if (FUSED) {
        bf16x4 o;
#pragma unroll
        for (int r = 0; r < 4; ++r) o[r] = (__bf16)v[r];
        *(bf16x4*)&((__bf16*)Cp)[(size_t)(orow + (mi << 4)) * LDQ + col0 + cl] = o;
      } else {
        *(f32x4*)&((float*)Cp)[(size_t)(orow + (mi << 4)) * 1024 + col0 + cl] = v;
      }
      sacc += v;
    }
    if (FUSED && region < 2) {
#pragma unroll
      for (int o = 1; o < 16; o <<= 1) {
        sacc[0] += __shfl_xor(sacc[0], o); sacc[1] += __shfl_xor(sacc[1], o);
        sacc[2] += __shfl_xor(sacc[2], o); sacc[3] += __shfl_xor(sacc[3], o);
      }
      if (lf == 0) {
        float* sums = (region == 0) ? qsum : ksum;
#pragma unroll
        for (int r = 0; r < 4; ++r) atomicAdd(&sums[b_of * 1024 + cb + r], sacc[r]);
      }
    }
  }
}

// ---------------- r2: si/so + accumulate qsi/kso ----------------
__global__ __launch_bounds__(256) void r2_flow(const __bf16* __restrict__ Qp, const __bf16* __restrict__ Kp,
                                               const float* __restrict__ ksum, const float* __restrict__ qsum,
                                               float* __restrict__ si,
                                               float* __restrict__ qsi, float* __restrict__ kso) {
  const int blk = blockIdx.x;
  const int chunk = blk & 15, bh = blk >> 4;
  const int b = bh >> 4, h = bh & 15;
  const int d = threadIdx.x & 63, w = threadIdx.x >> 6;
  __shared__ float ksE[64], qsE[64];
  if (threadIdx.x < 64) ksE[threadIdx.x] = ksum[bh * 64 + threadIdx.x] + EPSc;
  else if (threadIdx.x < 128) qsE[threadIdx.x - 64] = qsum[bh * 64 + threadIdx.x - 64] + EPSc;
  __syncthreads();
  const float kE = ksE[d], qE = qsE[d];
  const size_t base = ((size_t)b * Lc) * LDQ + h * 64 + d;
  const size_t obase = (size_t)bh * Lc;
  float qsia = 0.f, ksoa = 0.f;
  const int l0 = chunk * 256;
  for (int i = w; i < 256; i += 4) {
    const int l = l0 + i;
    const size_t idx = base + (size_t)l * LDQ;
    const float qv = (float)Qp[idx], kvv = (float)Kp[idx];
    float a = (qv + EPSc) * kE;
    float c2 = (kvv + EPSc) * qE;
#pragma unroll
    for (int o = 32; o; o >>= 1) { a += __shfl_xor(a, o); c2 += __shfl_xor(c2, o); }
    const float sil = 1.0f / a, sol = 1.0f / c2;
    if (d == 0) si[obase + l] = sil;
    qsia += qv * sil;
    ksoa += kvv * sol;
  }
  atomicAdd(&qsi[bh * 64 + d], qsia);
  atomicAdd(&kso[bh * 64 + d], ksoa);
}

// ---------------- r3: sink_allocation + exp(clipped conserved_source) + denom ----------------
__global__ __launch_bounds__(256) void r3_cons(const __bf16* __restrict__ Qp, const __bf16* __restrict__ Kp,
                                               const float* __restrict__ qsi, const float* __restrict__ kso,
                                               float* __restrict__ sa, float* __restrict__ csx,
                                               float* __restrict__ den) {
  const int blk = blockIdx.x;
  const int chunk = blk & 15, bh = blk >> 4;
  const int b = bh >> 4, h = bh & 15;
  const int d = threadIdx.x & 63, w = threadIdx.x >> 6;
  __shared__ float ksoE[64], qsiE[64];
  if (threadIdx.x < 64) ksoE[threadIdx.x] = kso[bh * 64 + threadIdx.x] + EPSc;
  else if (threadIdx.x < 128) qsiE[threadIdx.x - 64] = qsi[bh * 64 + threadIdx.x - 64] + EPSc;
  __syncthreads();
  const float kE = ksoE[d], qE = qsiE[d];
  const size_t base = ((size_t)b * Lc) * LDQ + h * 64 + d;
  const size_t obase = (size_t)bh * Lc;
  const int l0 = chunk * 256;
  float eacc = 0.f;
  for (int i = w; i < 256; i += 4) {
    const int l = l0 + i;
    const size_t idx = base + (size_t)l * LDQ;
    const float qv = (float)Qp[idx], kvv = (float)Kp[idx];
    float a = (qv + EPSc) * kE;
    float c2 = (kvv + EPSc) * qE;
#pragma unroll
    for (int o = 32; o; o >>= 1) { a += __shfl_xor(a, o); c2 += __shfl_xor(c2, o); }
    if (d == 0) {
      sa[obase + l] = 1.0f / (1.0f + expf(-a));
      const float cl = fminf(1.0f, fmaxf(-1.0f, c2));
      const float e = expf(cl);          // max-free softmax: cl in [-1,1]
      csx[obase + l] = e;
      eacc += e;
    }
  }
  if (d == 0) atomicAdd(&den[bh], eacc);
}

// ---------------- k5: kv[bh][d][m] = sum_l k * (v * scomp) ----------------
__global__ __launch_bounds__(256) void k5_kv(const __bf16* __restrict__ Kp, const __bf16* __restrict__ Vp,
                                             const float* __restrict__ csx, const float* __restrict__ den,
                                             float* __restrict__ kvout) {
  const int bh = blockIdx.x, chunk = blockIdx.y;  // chunk of 512 rows
  const int b = bh >> 4, h = bh & 15;
  const int tid = threadIdx.x;
  const int dq = (tid >> 4) << 2;
  const int mq = (tid & 15) << 2;
  const float sden = 4096.0f / den[bh];
  __shared__ float klds[4][64], vlds[4][64];
  float acc[4][4] = {};
  const int r = tid >> 6, c = tid & 63;
  const size_t rowbase = ((size_t)b * Lc + chunk * 512) * LDQ + h * 64;
  const size_t csbase = (size_t)bh * Lc + chunk * 512;
  for (int i = 0; i < 512; i += 4) {
    const size_t idx = rowbase + (size_t)(i + r) * LDQ + c;
    const float sc = csx[csbase + i + r] * sden;
    klds[r][c] = (float)Kp[idx];
    vlds[r][c] = (float)Vp[idx] * sc;
    __syncthreads();
#pragma unroll
    for (int rr = 0; rr < 4; ++rr) {
      float kr[4], vr[4];
#pragma unroll
      for (int j = 0; j < 4; ++j) { kr[j] = klds[rr][dq + j]; vr[j] = vlds[rr][mq + j]; }
#pragma unroll
      for (int a = 0; a < 4; ++a)
#pragma unroll
        for (int e = 0; e < 4; ++e) acc[a][e] += kr[a] * vr[e];
    }
    __syncthreads();
  }
#pragma unroll
  for (int a = 0; a < 4; ++a)
#pragma unroll
    for (int e = 0; e < 4; ++e)
      atomicAdd(&kvout[(size_t)bh * 4096 + (dq + a) * 64 + mq + e], acc[a][e]);
}

// ---------------- k6: x = (q*si) @ kv * sa, write bf16 ----------------
__global__ __launch_bounds__(256) void k6_x(const __bf16* __restrict__ Qp,
                                            const float* __restrict__ kvin, const float* __restrict__ si,
                                            const float* __restrict__ sa, __bf16* __restrict__ Xb) {
  const int bh = blockIdx.x, chunk = blockIdx.y;  // chunk of 256 rows
  const int b = bh >> 4, h = bh & 15;
  const int tid = threadIdx.x;
  __shared__ float kvs[4096];
  __shared__ float ql[64][65];
  for (int e = tid; e < 4096; e += 256) kvs[e] = kvin[(size_t)bh * 4096 + e];
  const int rr0 = (tid >> 4) << 2;
  const int mq = (tid & 15) << 2;
  const size_t bL = (size_t)b * Lc;
  const size_t obase = (size_t)bh * Lc;
  for (int g = 0; g < 4; ++g) {
    const int l0 = chunk * 256 + g * 64;
    __syncthreads();
    for (int e = tid; e < 4096; e += 256)
      ql[e >> 6][e & 63] = (float)Qp[(bL + l0 + (e >> 6)) * LDQ + h * 64 + (e & 63)];
    __syncthreads();
    float acc[4][4] = {};
#pragma unroll
    for (int d = 0; d < 64; ++d) {
      float kvr[4], qr[4];
#pragma unroll
      for (int j = 0; j < 4; ++j) { qr[j] = ql[rr0 + j][d]; kvr[j] = kvs[d * 64 + mq + j]; }
#pragma unroll
      for (int a = 0; a < 4; ++a)
#pragma unroll
        for (int e = 0; e < 4; ++e) acc[a][e] += qr[a] * kvr[e];
    }
#pragma unroll
    for (int a = 0; a < 4; ++a) {
      const int l = l0 + rr0 + a;
      const float sc = si[obase + l] * sa[obase + l];
      bf16x4 o;
#pragma unroll
      for (int e = 0; e < 4; ++e) o[e] = (__bf16)(acc[a][e] * sc);
      *(bf16x4*)&Xb[(bL + l) * Dc + h * 64 + mq] = o;
    }
  }
}

// ---------------- host ----------------
extern "C" void kernel_launch(void* const* d_in, const int* in_sizes, int n_in,
                              void* d_out, int out_size, void* d_ws, size_t ws_size,
                              hipStream_t stream) {
  const float* Qin = (const float*)d_in[0];
  const float* Kin = (const float*)d_in[1];
  const float* Vin = (const float*)d_in[2];
  const float* Wq = (const float*)d_in[3];
  const float* bq = (const float*)d_in[4];
  const float* Wk = (const float*)d_in[5];
  const float* bk = (const float*)d_in[6];
  const float* Wv = (const float*)d_in[7];
  const float* bv = (const float*)d_in[8];
  const float* Wo = (const float*)d_in[9];
  const float* bo = (const float*)d_in[10];

  const size_t MD = (size_t)Mc * Dc;
  __bf16* Aq = (__bf16*)d_ws;
  __bf16* Ak = Aq + MD;
  __bf16* Av = Ak + MD;
  __bf16* Wqt = Av + MD;
  __bf16* Wkt = Wqt + (size_t)Dc * Dc;
  __bf16* Wvt = Wkt + (size_t)Dc * Dc;
  __bf16* Wot = Wvt + (size_t)Dc * Dc;
  __bf16* QKV = Wot + (size_t)Dc * Dc;          // [M][3072]
  float* F = (float*)(QKV + (size_t)Mc * LDQ);
  float* ksum = F;              // 4096
  float* qsum = ksum + 4096;    // 4096
  float* kso = qsum + 4096;     // 4096
  float* qsi = kso + 4096;      // 4096
  float* den = qsi + 4096;      // 64
  float* kv = den + 64;         // 64*4096
  float* si = kv + 262144;
  float* sa = si + 262144;
  float* csx = sa + 262144;
  __bf16* Xb = Aq;              // reuse Aq (dead after QKV GEMM)

  hipMemsetAsync(F, 0, (size_t)(4 * 4096 + 64 + 262144) * sizeof(float), stream);

  const int n4blocks = (int)(MD / 4 / 256);
  conv_bf16<<<n4blocks, 256, 0, stream>>>(Qin, Aq);
  conv_bf16<<<n4blocks, 256, 0, stream>>>(Kin, Ak);
  conv_bf16<<<n4blocks, 256, 0, stream>>>(Vin, Av);
  dim3 wtg(32, 32), wtb(32, 8);
  wt_conv<<<wtg, wtb, 0, stream>>>(Wq, Wqt);
  wt_conv<<<wtg, wtb, 0, stream>>>(Wk, Wkt);
  wt_conv<<<wtg, wtb, 0, stream>>>(Wv, Wvt);
  wt_conv<<<wtg, wtb, 0, stream>>>(Wo, Wot);

  // fused grouped QKV projection: one dispatch, 768 blocks
  gemm256<1><<<dim3(64, 12), 512, 0, stream>>>(Aq, Ak, Av, Wqt, Wkt, Wvt,
                                               bq, bk, bv, QKV, qsum, ksum);

  const __bf16* Qp = QKV;
  const __bf16* Kp = QKV + 1024;
  const __bf16* Vp = QKV + 2048;
  r2_flow<<<1024, 256, 0, stream>>>(Qp, Kp, ksum, qsum, si, qsi, kso);
  r3_cons<<<1024, 256, 0, stream>>>(Qp, Kp, qsi, kso, sa, csx, den);
  k5_kv<<<dim3(64, 8), 256, 0, stream>>>(Kp, Vp, csx, den, kv);
  k6_x<<<dim3(64, 16), 256, 0, stream>>>(Qp, kv, si, sa, Xb);

  // output projection: fp32 out
  gemm256<0><<<dim3(64, 4), 512, 0, stream>>>(Xb, nullptr, nullptr, Wot, nullptr, nullptr,
                                              bo, nullptr, nullptr, d_out, nullptr, nullptr);
}

// Round 7
// 533.944 us; speedup vs baseline: 1.0023x; 1.0023x over previous
//
#include <hip/hip_runtime.h>

#define Bc 4
#define Lc 4096
#define Dc 1024
#define LDQ 3072
#define Mc (Bc*Lc)
#define EPSc 1e-6f

typedef __bf16 bf16x8 __attribute__((ext_vector_type(8)));
typedef __bf16 bf16x4 __attribute__((ext_vector_type(4)));
typedef float f32x4 __attribute__((ext_vector_type(4)));

typedef __attribute__((address_space(3))) void lds_vt;
typedef const __attribute__((address_space(1))) void gbl_vt;

__device__ __forceinline__ void gll16(const void* g, void* l) {
  __builtin_amdgcn_global_load_lds((gbl_vt*)g, (lds_vt*)l, 16, 0, 0);
}

// ---------------- converts ----------------
__global__ __launch_bounds__(256) void conv_bf16(const float* __restrict__ X, __bf16* __restrict__ Y) {
  const int i = blockIdx.x * 256 + threadIdx.x;
  const float4 v = ((const float4*)X)[i];
  bf16x4 o;
  o[0] = (__bf16)v.x; o[1] = (__bf16)v.y; o[2] = (__bf16)v.z; o[3] = (__bf16)v.w;
  ((bf16x4*)Y)[i] = o;
}

__global__ __launch_bounds__(256) void wt_conv(const float* __restrict__ W, __bf16* __restrict__ Wt) {
  __shared__ float t[32][33];
  const int n0 = blockIdx.x << 5, k0 = blockIdx.y << 5;
  const int tx = threadIdx.x, ty = threadIdx.y;  // block (32,8)
#pragma unroll
  for (int i = 0; i < 4; ++i)
    t[ty + 8 * i][tx] = W[(size_t)(k0 + ty + 8 * i) * Dc + n0 + tx];
  __syncthreads();
#pragma unroll
  for (int i = 0; i < 4; ++i)
    Wt[(size_t)(n0 + ty + 8 * i) * Dc + k0 + tx] = (__bf16)t[tx][ty + 8 * i];
}

// ---------------- GEMM 128x128, BK=32, single-buffer LDS, m97 structure ----------------
// 4 waves (2x2), each 64x64 out (4x4 16x16x32 frags). 16KB LDS -> 3 blocks/CU.
// Per K-step: 16 gll16 (block) -> sync -> 8 ds_read_b128 + 16 MFMA (per wave) -> sync.
// LDS granule swizzle g' = g ^ ((row>>1)&3): conflict-free frag reads; applied as
// pre-swizzled global SOURCE + swizzled ds_read granule (linear gll16 dest).
// FUSED=1: grouped QKV projection (sigmoid Q,K; col-sum atomics; bf16 out ld=3072).
// FUSED=0: plain C = A@Wt^T + bias, fp32 out ld=1024.
// MFMA operands swapped (mfma(B,A)) so each lane holds 4 consecutive out-cols.
template <int FUSED>
__global__ __launch_bounds__(256, 3) void gemm128(
    const __bf16* __restrict__ Aq_, const __bf16* __restrict__ Ak_, const __bf16* __restrict__ Av_,
    const __bf16* __restrict__ Wq_, const __bf16* __restrict__ Wk_, const __bf16* __restrict__ Wv_,
    const float* __restrict__ bq_, const float* __restrict__ bk_, const float* __restrict__ bv_,
    void* __restrict__ Cp, float* __restrict__ qsum, float* __restrict__ ksum) {
  __shared__ __bf16 As[128 * 32];
  __shared__ __bf16 Bs[128 * 32];
  const int tid = threadIdx.x;
  const int lane = tid & 63, w4 = tid >> 6;
  const int wr = w4 >> 1, wc = w4 & 1;          // 2 x 2 waves, 64x64 each
  const int lf = lane & 15, kq = lane >> 4;

  // XCD-chunked bijective swizzle, cols fastest (A-panel L2 reuse per XCD)
  constexpr int NCT = FUSED ? 24 : 8;
  constexpr int CPX = (128 * NCT) >> 3;
  const int hwlin = blockIdx.x + (blockIdx.y << 7);
  const int swz = (hwlin & 7) * CPX + (hwlin >> 3);
  const int bx = swz / NCT, ct = swz - bx * NCT;
  const int row0 = bx << 7, col0 = ct << 7;
  const int region = FUSED ? (ct >> 3) : 0;
  const int colL = FUSED ? (col0 & 1023) : col0;

  const __bf16* Agl = FUSED ? (region == 0 ? Aq_ : (region == 1 ? Ak_ : Av_)) : Aq_;
  const __bf16* Bgl = FUSED ? (region == 0 ? Wq_ : (region == 1 ? Wk_ : Wv_)) : Wq_;
  const float* biasp = FUSED ? (region == 0 ? bq_ : (region == 1 ? bk_ : bv_)) : bq_;
  const __bf16* Ab_g = Agl + (size_t)row0 * 1024;
  const __bf16* Bb_g = Bgl + (size_t)colL * 1024;

  // Staging: each wave stages A rows [w4*32,+32) and B rows [w4*32,+32), 2 instr each.
  // lane l in instr (half): row = w4*32 + half*16 + (l>>2), dest granule gd = l&3,
  // source k-granule = gd ^ ((l>>3)&3)   [since (row>>1)&3 == ((l>>2)>>1)&3].
  const int srow = (w4 << 5) + (lane >> 2);
  const int sgd = lane & 3;
  const int ssrc = (sgd ^ ((lane >> 3) & 3)) << 3;          // src elem offset in k
  const size_t aoff0 = (size_t)srow * 1024 + ssrc;
  const size_t aoff1 = (size_t)(srow + 16) * 1024 + ssrc;
  const int ldst0 = srow * 32 + (sgd << 3);
  const int ldst1 = (srow + 16) * 32 + (sgd << 3);

  // Fragment reads: A frag m: row = wr*64 + m*16 + lf, granule kq ^ ((lf>>1)&3); B same with wc.
  const int kgsw = (kq ^ ((lf >> 1) & 3)) << 3;
  const int arb = (wr * 64 + lf) * 32 + kgsw;
  const int brb = (wc * 64 + lf) * 32 + kgsw;

  f32x4 acc[4][4] = {};

  for (int t = 0; t < 32; ++t) {
    const int kb = t << 5;
    gll16(Ab_g + aoff0 + kb, &As[ldst0]);
    gll16(Ab_g + aoff1 + kb, &As[ldst1]);
    gll16(Bb_g + aoff0 + kb, &Bs[ldst0]);
    gll16(Bb_g + aoff1 + kb, &Bs[ldst1]);
    __syncthreads();
    bf16x8 af[4], bfr[4];
#pragma unroll
    for (int m = 0; m < 4; ++m) af[m] = *(const bf16x8*)(As + arb + m * 512);
#pragma unroll
    for (int n = 0; n < 4; ++n) bfr[n] = *(const bf16x8*)(Bs + brb + n * 512);
#pragma unroll
    for (int m = 0; m < 4; ++m)
#pragma unroll
      for (int n = 0; n < 4; ++n)
        acc[m][n] = __builtin_amdgcn_mfma_f32_16x16x32_bf16(bfr[n], af[m], acc[m][n], 0, 0, 0);
    __syncthreads();
  }

  // epilogue: acc[m][n][r] = C[row0 + wr*64 + m*16 + lf][col0 + wc*64 + n*16 + kq*4 + r]
  const int b_of = row0 >> 12;
  const int orow = row0 + wr * 64 + lf;
  const int ocl = wc * 64 + (kq << 2);
#pragma unroll
  for (int n = 0; n < 4; ++n) {
    const int cl = ocl + (n << 4);           // 0..127 within tile
    const int cb = colL + cl;                // bias/sum col (0..1023)
    const f32x4 bb = *(const f32x4*)&biasp[cb];
    f32x4 sacc = {0.f, 0.f, 0.f, 0.f};
#pragma unroll
    for (int m = 0; m < 4; ++m) {
      f32x4 v = acc[m][n] + bb;
      if (FUSED && region < 2) {
#pragma unroll
        for (int r = 0; r < 4; ++r) v[r] = 1.0f / (1.0f + expf(-v[r]));
      }
      if (FUSED) {
        bf16x4 o;
#pragma unroll
        for (int r = 0; r < 4; ++r) o[r] = (__bf16)v[r];
        *(bf16x4*)&((__bf16*)Cp)[(size_t)(orow + (m << 4)) * LDQ + col0 + cl] = o;
      } else {
        *(f32x4*)&((float*)Cp)[(size_t)(orow + (m << 4)) * 1024 + col0 + cl] = v;
      }
      sacc += v;
    }
    if (FUSED && region < 2) {
#pragma unroll
      for (int o = 1; o < 16; o <<= 1) {
        sacc[0] += __shfl_xor(sacc[0], o); sacc[1] += __shfl_xor(sacc[1], o);
        sacc[2] += __shfl_xor(sacc[2], o); sacc[3] += __shfl_xor(sacc[3], o);
      }
      if (lf == 0) {
        float* sums = (region == 0) ? qsum : ksum;
#pragma unroll
        for (int r = 0; r < 4; ++r) atomicAdd(&sums[b_of * 1024 + cb + r], sacc[r]);
      }
    }
  }
}

// ---------------- r2: si/so + accumulate qsi/kso ----------------
__global__ __launch_bounds__(256) void r2_flow(const __bf16* __restrict__ Qp, const __bf16* __restrict__ Kp,
                                               const float* __restrict__ ksum, const float* __restrict__ qsum,
                                               float* __restrict__ si,
                                               float* __restrict__ qsi, float* __restrict__ kso) {
  const int blk = blockIdx.x;
  const int chunk = blk & 15, bh = blk >> 4;
  const int b = bh >> 4, h = bh & 15;
  const int d = threadIdx.x & 63, w = threadIdx.x >> 6;
  __shared__ float ksE[64], qsE[64];
  if (threadIdx.x < 64) ksE[threadIdx.x] = ksum[bh * 64 + threadIdx.x] + EPSc;
  else if (threadIdx.x < 128) qsE[threadIdx.x - 64] = qsum[bh * 64 + threadIdx.x - 64] + EPSc;
  __syncthreads();
  const float kE = ksE[d], qE = qsE[d];
  const size_t base = ((size_t)b * Lc) * LDQ + h * 64 + d;
  const size_t obase = (size_t)bh * Lc;
  float qsia = 0.f, ksoa = 0.f;
  const int l0 = chunk * 256;
  for (int i = w; i < 256; i += 4) {
    const int l = l0 + i;
    const size_t idx = base + (size_t)l * LDQ;
    const float qv = (float)Qp[idx], kvv = (float)Kp[idx];
    float a = (qv + EPSc) * kE;
    float c2 = (kvv + EPSc) * qE;
#pragma unroll
    for (int o = 32; o; o >>= 1) { a += __shfl_xor(a, o); c2 += __shfl_xor(c2, o); }
    const float sil = 1.0f / a, sol = 1.0f / c2;
    if (d == 0) si[obase + l] = sil;
    qsia += qv * sil;
    ksoa += kvv * sol;
  }
  atomicAdd(&qsi[bh * 64 + d], qsia);
  atomicAdd(&kso[bh * 64 + d], ksoa);
}

// ---------------- r3: sink_allocation + exp(clipped conserved_source) + denom ----------------
__global__ __launch_bounds__(256) void r3_cons(const __bf16* __restrict__ Qp, const __bf16* __restrict__ Kp,
                                               const float* __restrict__ qsi, const float* __restrict__ kso,
                                               float* __restrict__ sa, float* __restrict__ csx,
                                               float* __restrict__ den) {
  const int blk = blockIdx.x;
  const int chunk = blk & 15, bh = blk >> 4;
  const int b = bh >> 4, h = bh & 15;
  const int d = threadIdx.x & 63, w = threadIdx.x >> 6;
  __shared__ float ksoE[64], qsiE[64];
  if (threadIdx.x < 64) ksoE[threadIdx.x] = kso[bh * 64 + threadIdx.x] + EPSc;
  else if (threadIdx.x < 128) qsiE[threadIdx.x - 64] = qsi[bh * 64 + threadIdx.x - 64] + EPSc;
  __syncthreads();
  const float kE = ksoE[d], qE = qsiE[d];
  const size_t base = ((size_t)b * Lc) * LDQ + h * 64 + d;
  const size_t obase = (size_t)bh * Lc;
  const int l0 = chunk * 256;
  float eacc = 0.f;
  for (int i = w; i < 256; i += 4) {
    const int l = l0 + i;
    const size_t idx = base + (size_t)l * LDQ;
    const float qv = (float)Qp[idx], kvv = (float)Kp[idx];
    float a = (qv + EPSc) * kE;
    float c2 = (kvv + EPSc) * qE;
#pragma unroll
    for (int o = 32; o; o >>= 1) { a += __shfl_xor(a, o); c2 += __shfl_xor(c2, o); }
    if (d == 0) {
      sa[obase + l] = 1.0f / (1.0f + expf(-a));
      const float cl = fminf(1.0f, fmaxf(-1.0f, c2));
      const float e = expf(cl);          // max-free softmax: cl in [-1,1]
      csx[obase + l] = e;
      eacc += e;
    }
  }
  if (d == 0) atomicAdd(&den[bh], eacc);
}

// ---------------- k5: kv[bh][d][m] = sum_l k * (v * scomp) ----------------
__global__ __launch_bounds__(256) void k5_kv(const __bf16* __restrict__ Kp, const __bf16* __restrict__ Vp,
                                             const float* __restrict__ csx, const float* __restrict__ den,
                                             float* __restrict__ kvout) {
  const int bh = blockIdx.x, chunk = blockIdx.y;  // chunk of 512 rows
  const int b = bh >> 4, h = bh & 15;
  const int tid = threadIdx.x;
  const int dq = (tid >> 4) << 2;
  const int mq = (tid & 15) << 2;
  const float sden = 4096.0f / den[bh];
  __shared__ float klds[4][64], vlds[4][64];
  float acc[4][4] = {};
  const int r = tid >> 6, c = tid & 63;
  const size_t rowbase = ((size_t)b * Lc + chunk * 512) * LDQ + h * 64;
  const size_t csbase = (size_t)bh * Lc + chunk * 512;
  for (int i = 0; i < 512; i += 4) {
    const size_t idx = rowbase + (size_t)(i + r) * LDQ + c;
    const float sc = csx[csbase + i + r] * sden;
    klds[r][c] = (float)Kp[idx];
    vlds[r][c] = (float)Vp[idx] * sc;
    __syncthreads();
#pragma unroll
    for (int rr = 0; rr < 4; ++rr) {
      float kr[4], vr[4];
#pragma unroll
      for (int j = 0; j < 4; ++j) { kr[j] = klds[rr][dq + j]; vr[j] = vlds[rr][mq + j]; }
#pragma unroll
      for (int a = 0; a < 4; ++a)
#pragma unroll
        for (int e = 0; e < 4; ++e) acc[a][e] += kr[a] * vr[e];
    }
    __syncthreads();
  }
#pragma unroll
  for (int a = 0; a < 4; ++a)
#pragma unroll
    for (int e = 0; e < 4; ++e)
      atomicAdd(&kvout[(size_t)bh * 4096 + (dq + a) * 64 + mq + e], acc[a][e]);
}

// ---------------- k6: x = (q*si) @ kv * sa, write bf16 ----------------
__global__ __launch_bounds__(256) void k6_x(const __bf16* __restrict__ Qp,
                                            const float* __restrict__ kvin, const float* __restrict__ si,
                                            const float* __restrict__ sa, __bf16* __restrict__ Xb) {
  const int bh = blockIdx.x, chunk = blockIdx.y;  // chunk of 256 rows
  const int b = bh >> 4, h = bh & 15;
  const int tid = threadIdx.x;
  __shared__ float kvs[4096];
  __shared__ float ql[64][65];
  for (int e = tid; e < 4096; e += 256) kvs[e] = kvin[(size_t)bh * 4096 + e];
  const int rr0 = (tid >> 4) << 2;
  const int mq = (tid & 15) << 2;
  const size_t bL = (size_t)b * Lc;
  const size_t obase = (size_t)bh * Lc;
  for (int g = 0; g < 4; ++g) {
    const int l0 = chunk * 256 + g * 64;
    __syncthreads();
    for (int e = tid; e < 4096; e += 256)
      ql[e >> 6][e & 63] = (float)Qp[(bL + l0 + (e >> 6)) * LDQ + h * 64 + (e & 63)];
    __syncthreads();
    float acc[4][4] = {};
#pragma unroll
    for (int d = 0; d < 64; ++d) {
      float kvr[4], qr[4];
#pragma unroll
      for (int j = 0; j < 4; ++j) { qr[j] = ql[rr0 + j][d]; kvr[j] = kvs[d * 64 + mq + j]; }
#pragma unroll
      for (int a = 0; a < 4; ++a)
#pragma unroll
        for (int e = 0; e < 4; ++e) acc[a][e] += qr[a] * kvr[e];
    }
#pragma unroll
    for (int a = 0; a < 4; ++a) {
      const int l = l0 + rr0 + a;
      const float sc = si[obase + l] * sa[obase + l];
      bf16x4 o;
#pragma unroll
      for (int e = 0; e < 4; ++e) o[e] = (__bf16)(acc[a][e] * sc);
      *(bf16x4*)&Xb[(bL + l) * Dc + h * 64 + mq] = o;
    }
  }
}

// ---------------- host ----------------
extern "C" void kernel_launch(void* const* d_in, const int* in_sizes, int n_in,
                              void* d_out, int out_size, void* d_ws, size_t ws_size,
                              hipStream_t stream) {
  const float* Qin = (const float*)d_in[0];
  const float* Kin = (const float*)d_in[1];
  const float* Vin = (const float*)d_in[2];
  const float* Wq = (const float*)d_in[3];
  const float* bq = (const float*)d_in[4];
  const float* Wk = (const float*)d_in[5];
  const float* bk = (const float*)d_in[6];
  const float* Wv = (const float*)d_in[7];
  const float* bv = (const float*)d_in[8];
  const float* Wo = (const float*)d_in[9];
  const float* bo = (const float*)d_in[10];

  const size_t MD = (size_t)Mc * Dc;
  __bf16* Aq = (__bf16*)d_ws;
  __bf16* Ak = Aq + MD;
  __bf16* Av = Ak + MD;
  __bf16* Wqt = Av + MD;
  __bf16* Wkt = Wqt + (size_t)Dc * Dc;
  __bf16* Wvt = Wkt + (size_t)Dc * Dc;
  __bf16* Wot = Wvt + (size_t)Dc * Dc;
  __bf16* QKV = Wot + (size_t)Dc * Dc;          // [M][3072]
  float* F = (float*)(QKV + (size_t)Mc * LDQ);
  float* ksum = F;              // 4096
  float* qsum = ksum + 4096;    // 4096
  float* kso = qsum + 4096;     // 4096
  float* qsi = kso + 4096;      // 4096
  float* den = qsi + 4096;      // 64
  float* kv = den + 64;         // 64*4096
  float* si = kv + 262144;
  float* sa = si + 262144;
  float* csx = sa + 262144;
  __bf16* Xb = Aq;              // reuse Aq (dead after QKV GEMM)

  hipMemsetAsync(F, 0, (size_t)(4 * 4096 + 64 + 262144) * sizeof(float), stream);

  const int n4blocks = (int)(MD / 4 / 256);
  conv_bf16<<<n4blocks, 256, 0, stream>>>(Qin, Aq);
  conv_bf16<<<n4blocks, 256, 0, stream>>>(Kin, Ak);
  conv_bf16<<<n4blocks, 256, 0, stream>>>(Vin, Av);
  dim3 wtg(32, 32), wtb(32, 8);
  wt_conv<<<wtg, wtb, 0, stream>>>(Wq, Wqt);
  wt_conv<<<wtg, wtb, 0, stream>>>(Wk, Wkt);
  wt_conv<<<wtg, wtb, 0, stream>>>(Wv, Wvt);
  wt_conv<<<wtg, wtb, 0, stream>>>(Wo, Wot);

  // fused grouped QKV projection: one dispatch, 3072 blocks of 128x128
  gemm128<1><<<dim3(128, 24), 256, 0, stream>>>(Aq, Ak, Av, Wqt, Wkt, Wvt,
                                                bq, bk, bv, QKV, qsum, ksum);

  const __bf16* Qp = QKV;
  const __bf16* Kp = QKV + 1024;
  const __bf16* Vp = QKV + 2048;
  r2_flow<<<1024, 256, 0, stream>>>(Qp, Kp, ksum, qsum, si, qsi, kso);
  r3_cons<<<1024, 256, 0, stream>>>(Qp, Kp, qsi, kso, sa, csx, den);
  k5_kv<<<dim3(64, 8), 256, 0, stream>>>(Kp, Vp, csx, den, kv);
  k6_x<<<dim3(64, 16), 256, 0, stream>>>(Qp, kv, si, sa, Xb);

  // output projection: fp32 out, 1024 blocks of 128x128
  gemm128<0><<<dim3(128, 8), 256, 0, stream>>>(Xb, nullptr, nullptr, Wot, nullptr, nullptr,
                                               bo, nullptr, nullptr, d_out, nullptr, nullptr);
}

// Round 10
// 522.527 us; speedup vs baseline: 1.0242x; 1.0218x over previous
//
#include <hip/hip_runtime.h>

#define Bc 4
#define Lc 4096
#define Dc 1024
#define LDQ 3072
#define Mc (Bc*Lc)
#define EPSc 1e-6f

typedef __bf16 bf16x8 __attribute__((ext_vector_type(8)));
typedef __bf16 bf16x4 __attribute__((ext_vector_type(4)));
typedef float f32x4 __attribute__((ext_vector_type(4)));

typedef __attribute__((address_space(3))) void lds_vt;
typedef const __attribute__((address_space(1))) void gbl_vt;

__device__ __forceinline__ void gll16(const void* g, void* l) {
  __builtin_amdgcn_global_load_lds((gbl_vt*)g, (lds_vt*)l, 16, 0, 0);
}

// ---------------- fused converts (validated mechanics, z/y-dispatch wrappers) ----------------
__global__ __launch_bounds__(256) void conv3(const float* __restrict__ Q, const float* __restrict__ K,
                                             const float* __restrict__ V, __bf16* __restrict__ Y) {
  const float* src = (blockIdx.y == 0) ? Q : (blockIdx.y == 1) ? K : V;
  __bf16* dst = Y + (size_t)blockIdx.y * ((size_t)Mc * Dc);
  const int i = blockIdx.x * 256 + threadIdx.x;
  const float4 v = ((const float4*)src)[i];
  bf16x4 o;
  o[0] = (__bf16)v.x; o[1] = (__bf16)v.y; o[2] = (__bf16)v.z; o[3] = (__bf16)v.w;
  ((bf16x4*)dst)[i] = o;
}

__global__ __launch_bounds__(256) void wt_conv4(const float* __restrict__ W0, const float* __restrict__ W1,
                                                const float* __restrict__ W2, const float* __restrict__ W3,
                                                __bf16* __restrict__ T) {
  const float* W = (blockIdx.z == 0) ? W0 : (blockIdx.z == 1) ? W1 : (blockIdx.z == 2) ? W2 : W3;
  __bf16* Wt = T + (size_t)blockIdx.z * ((size_t)Dc * Dc);
  __shared__ float t[32][33];
  const int n0 = blockIdx.x << 5, k0 = blockIdx.y << 5;
  const int tx = threadIdx.x, ty = threadIdx.y;  // block (32,8)
#pragma unroll
  for (int i = 0; i < 4; ++i)
    t[ty + 8 * i][tx] = W[(size_t)(k0 + ty + 8 * i) * Dc + n0 + tx];
  __syncthreads();
#pragma unroll
  for (int i = 0; i < 4; ++i)
    Wt[(size_t)(n0 + ty + 8 * i) * Dc + k0 + tx] = (__bf16)t[tx][ty + 8 * i];
}

// ---------------- GEMM 128x128, BK=32, single-buffer LDS, m97 structure (r7-validated) -----
template <int FUSED>
__global__ __launch_bounds__(256, 4) void gemm128(
    const __bf16* __restrict__ Aq_, const __bf16* __restrict__ Ak_, const __bf16* __restrict__ Av_,
    const __bf16* __restrict__ Wq_, const __bf16* __restrict__ Wk_, const __bf16* __restrict__ Wv_,
    const float* __restrict__ bq_, const float* __restrict__ bk_, const float* __restrict__ bv_,
    void* __restrict__ Cp, float* __restrict__ qsum, float* __restrict__ ksum) {
  __shared__ __bf16 As[128 * 32];
  __shared__ __bf16 Bs[128 * 32];
  const int tid = threadIdx.x;
  const int lane = tid & 63, w4 = tid >> 6;
  const int wr = w4 >> 1, wc = w4 & 1;          // 2 x 2 waves, 64x64 each
  const int lf = lane & 15, kq = lane >> 4;

  constexpr int NCT = FUSED ? 24 : 8;
  constexpr int CPX = (128 * NCT) >> 3;
  const int hwlin = blockIdx.x + (blockIdx.y << 7);
  const int swz = (hwlin & 7) * CPX + (hwlin >> 3);
  const int bx = swz / NCT, ct = swz - bx * NCT;
  const int row0 = bx << 7, col0 = ct << 7;
  const int region = FUSED ? (ct >> 3) : 0;
  const int colL = FUSED ? (col0 & 1023) : col0;

  const __bf16* Agl = FUSED ? (region == 0 ? Aq_ : (region == 1 ? Ak_ : Av_)) : Aq_;
  const __bf16* Bgl = FUSED ? (region == 0 ? Wq_ : (region == 1 ? Wk_ : Wv_)) : Wq_;
  const float* biasp = FUSED ? (region == 0 ? bq_ : (region == 1 ? bk_ : bv_)) : bq_;
  const __bf16* Ab_g = Agl + (size_t)row0 * 1024;
  const __bf16* Bb_g = Bgl + (size_t)colL * 1024;

  const int srow = (w4 << 5) + (lane >> 2);
  const int sgd = lane & 3;
  const int ssrc = (sgd ^ ((lane >> 3) & 3)) << 3;
  const size_t aoff0 = (size_t)srow * 1024 + ssrc;
  const size_t aoff1 = (size_t)(srow + 16) * 1024 + ssrc;
  const int ldst0 = srow * 32 + (sgd << 3);
  const int ldst1 = (srow + 16) * 32 + (sgd << 3);

  const int kgsw = (kq ^ ((lf >> 1) & 3)) << 3;
  const int arb = (wr * 64 + lf) * 32 + kgsw;
  const int brb = (wc * 64 + lf) * 32 + kgsw;

  f32x4 acc[4][4] = {};

  for (int t = 0; t < 32; ++t) {
    const int kb = t << 5;
    gll16(Ab_g + aoff0 + kb, &As[ldst0]);
    gll16(Ab_g + aoff1 + kb, &As[ldst1]);
    gll16(Bb_g + aoff0 + kb, &Bs[ldst0]);
    gll16(Bb_g + aoff1 + kb, &Bs[ldst1]);
    __syncthreads();
    bf16x8 af[4], bfr[4];
#pragma unroll
    for (int m = 0; m < 4; ++m) af[m] = *(const bf16x8*)(As + arb + m * 512);
#pragma unroll
    for (int n = 0; n < 4; ++n) bfr[n] = *(const bf16x8*)(Bs + brb + n * 512);
#pragma unroll
    for (int m = 0; m < 4; ++m)
#pragma unroll
      for (int n = 0; n < 4; ++n)
        acc[m][n] = __builtin_amdgcn_mfma_f32_16x16x32_bf16(bfr[n], af[m], acc[m][n], 0, 0, 0);
    __syncthreads();
  }

  const int b_of = row0 >> 12;
  const int orow = row0 + wr * 64 + lf;
  const int ocl = wc * 64 + (kq << 2);
#pragma unroll
  for (int n = 0; n < 4; ++n) {
    const int cl = ocl + (n << 4);
    const int cb = colL + cl;
    const f32x4 bb = *(const f32x4*)&biasp[cb];
    f32x4 sacc = {0.f, 0.f, 0.f, 0.f};
#pragma unroll
    for (int m = 0; m < 4; ++m) {
      f32x4 v = acc[m][n] + bb;
      if (FUSED && region < 2) {
#pragma unroll
        for (int r = 0; r < 4; ++r) v[r] = 1.0f / (1.0f + expf(-v[r]));
      }
      if (FUSED) {
        bf16x4 o;
#pragma unroll
        for (int r = 0; r < 4; ++r) o[r] = (__bf16)v[r];
        *(bf16x4*)&((__bf16*)Cp)[(size_t)(orow + (m << 4)) * LDQ + col0 + cl] = o;
      } else {
        *(f32x4*)&((float*)Cp)[(size_t)(orow + (m << 4)) * 1024 + col0 + cl] = v;
      }
      sacc += v;
    }
    if (FUSED && region < 2) {
#pragma unroll
      for (int o = 1; o < 16; o <<= 1) {
        sacc[0] += __shfl_xor(sacc[0], o); sacc[1] += __shfl_xor(sacc[1], o);
        sacc[2] += __shfl_xor(sacc[2], o); sacc[3] += __shfl_xor(sacc[3], o);
      }
      if (lf == 0) {
        float* sums = (region == 0) ? qsum : ksum;
#pragma unroll
        for (int r = 0; r < 4; ++r) atomicAdd(&sums[b_of * 1024 + cb + r], sacc[r]);
      }
    }
  }
}

// ---------------- r2: si + qsi/kso (round-7-validated shuffle form) ----------------
__global__ __launch_bounds__(256) void r2_flow(const __bf16* __restrict__ Qp, const __bf16* __restrict__ Kp,
                                               const float* __restrict__ ksum, const float* __restrict__ qsum,
                                               float* __restrict__ si,
                                               float* __restrict__ qsi, float* __restrict__ kso) {
  const int blk = blockIdx.x;
  const int chunk = blk & 15, bh = blk >> 4;
  const int b = bh >> 4, h = bh & 15;
  const int d = threadIdx.x & 63, w = threadIdx.x >> 6;
  __shared__ float ksE[64], qsE[64];
  if (threadIdx.x < 64) ksE[threadIdx.x] = ksum[bh * 64 + threadIdx.x] + EPSc;
  else if (threadIdx.x < 128) qsE[threadIdx.x - 64] = qsum[bh * 64 + threadIdx.x - 64] + EPSc;
  __syncthreads();
  const float kE = ksE[d], qE = qsE[d];
  const size_t base = ((size_t)b * Lc) * LDQ + h * 64 + d;
  const size_t obase = (size_t)bh * Lc;
  float qsia = 0.f, ksoa = 0.f;
  const int l0 = chunk * 256;
  for (int i = w; i < 256; i += 4) {
    const int l = l0 + i;
    const size_t idx = base + (size_t)l * LDQ;
    const float qv = (float)Qp[idx], kvv = (float)Kp[idx];
    float a = (qv + EPSc) * kE;
    float c2 = (kvv + EPSc) * qE;
#pragma unroll
    for (int o = 32; o; o >>= 1) { a += __shfl_xor(a, o); c2 += __shfl_xor(c2, o); }
    const float sil = 1.0f / a, sol = 1.0f / c2;
    if (d == 0) si[obase + l] = sil;
    qsia += qv * sil;
    ksoa += kvv * sol;
  }
  atomicAdd(&qsi[bh * 64 + d], qsia);
  atomicAdd(&kso[bh * 64 + d], ksoa);
}

// ---------------- r3: sa + csx + den (round-7-validated) ----------------
__global__ __launch_bounds__(256) void r3_cons(const __bf16* __restrict__ Qp, const __bf16* __restrict__ Kp,
                                               const float* __restrict__ qsi, const float* __restrict__ kso,
                                               float* __restrict__ sa, float* __restrict__ csx,
                                               float* __restrict__ den) {
  const int blk = blockIdx.x;
  const int chunk = blk & 15, bh = blk >> 4;
  const int b = bh >> 4, h = bh & 15;
  const int d = threadIdx.x & 63, w = threadIdx.x >> 6;
  __shared__ float ksoE[64], qsiE[64];
  if (threadIdx.x < 64) ksoE[threadIdx.x] = kso[bh * 64 + threadIdx.x] + EPSc;
  else if (threadIdx.x < 128) qsiE[threadIdx.x - 64] = qsi[bh * 64 + threadIdx.x - 64] + EPSc;
  __syncthreads();
  const float kE = ksoE[d], qE = qsiE[d];
  const size_t base = ((size_t)b * Lc) * LDQ + h * 64 + d;
  const size_t obase = (size_t)bh * Lc;
  const int l0 = chunk * 256;
  float eacc = 0.f;
  for (int i = w; i < 256; i += 4) {
    const int l = l0 + i;
    const size_t idx = base + (size_t)l * LDQ;
    const float qv = (float)Qp[idx], kvv = (float)Kp[idx];
    float a = (qv + EPSc) * kE;
    float c2 = (kvv + EPSc) * qE;
#pragma unroll
    for (int o = 32; o; o >>= 1) { a += __shfl_xor(a, o); c2 += __shfl_xor(c2, o); }
    if (d == 0) {
      sa[obase + l] = 1.0f / (1.0f + expf(-a));
      const float cl = fminf(1.0f, fmaxf(-1.0f, c2));
      const float e = expf(cl);          // max-free softmax: cl in [-1,1]
      csx[obase + l] = e;
      eacc += e;
    }
  }
  if (d == 0) atomicAdd(&den[bh], eacc);
}

// ---------------- k5: kv[d][m] = sum_l k * (v * scomp)  (round-7-validated) ----------------
__global__ __launch_bounds__(256) void k5_kv(const __bf16* __restrict__ Kp, const __bf16* __restrict__ Vp,
                                             const float* __restrict__ csx, const float* __restrict__ den,
                                             float* __restrict__ kvout) {
  const int bh = blockIdx.x, chunk = blockIdx.y;  // chunk of 512 rows
  const int b = bh >> 4, h = bh & 15;
  const int tid = threadIdx.x;
  const int dq = (tid >> 4) << 2;
  const int mq = (tid & 15) << 2;
  const float sden = 4096.0f / den[bh];
  __shared__ float klds[4][64], vlds[4][64];
  float acc[4][4] = {};
  const int r = tid >> 6, c = tid & 63;
  const size_t rowbase = ((size_t)b * Lc + chunk * 512) * LDQ + h * 64;
  const size_t csbase = (size_t)bh * Lc + chunk * 512;
  for (int i = 0; i < 512; i += 4) {
    const size_t idx = rowbase + (size_t)(i + r) * LDQ + c;
    const float sc = csx[csbase + i + r] * sden;
    klds[r][c] = (float)Kp[idx];
    vlds[r][c] = (float)Vp[idx] * sc;
    __syncthreads();
#pragma unroll
    for (int rr = 0; rr < 4; ++rr) {
      float kr[4], vr[4];
#pragma unroll
      for (int j = 0; j < 4; ++j) { kr[j] = klds[rr][dq + j]; vr[j] = vlds[rr][mq + j]; }
#pragma unroll
      for (int a = 0; a < 4; ++a)
#pragma unroll
        for (int e = 0; e < 4; ++e) acc[a][e] += kr[a] * vr[e];
    }
    __syncthreads();
  }
#pragma unroll
  for (int a = 0; a < 4; ++a)
#pragma unroll
    for (int e = 0; e < 4; ++e)
      atomicAdd(&kvout[(size_t)bh * 4096 + (dq + a) * 64 + mq + e], acc[a][e]);
}

// ---------------- k6: x = (q*si) @ kv * sa, f32 VALU (round-7-validated) ----------------
__global__ __launch_bounds__(256) void k6_x(const __bf16* __restrict__ Qp,
                                            const float* __restrict__ kvin, const float* __restrict__ si,
                                            const float* __restrict__ sa, __bf16* __restrict__ Xb) {
  const int bh = blockIdx.x, chunk = blockIdx.y;  // chunk of 256 rows
  const int b = bh >> 4, h = bh & 15;
  const int tid = threadIdx.x;
  __shared__ float kvs[4096];
  __shared__ float ql[64][65];
  for (int e = tid; e < 4096; e += 256) kvs[e] = kvin[(size_t)bh * 4096 + e];
  const int rr0 = (tid >> 4) << 2;
  const int mq = (tid & 15) << 2;
  const size_t bL = (size_t)b * Lc;
  const size_t obase = (size_t)bh * Lc;
  for (int g = 0; g < 4; ++g) {
    const int l0 = chunk * 256 + g * 64;
    __syncthreads();
    for (int e = tid; e < 4096; e += 256)
      ql[e >> 6][e & 63] = (float)Qp[(bL + l0 + (e >> 6)) * LDQ + h * 64 + (e & 63)];
    __syncthreads();
    float acc[4][4] = {};
#pragma unroll
    for (int d = 0; d < 64; ++d) {
      float kvr[4], qr[4];
#pragma unroll
      for (int j = 0; j < 4; ++j) { qr[j] = ql[rr0 + j][d]; kvr[j] = kvs[d * 64 + mq + j]; }
#pragma unroll
      for (int a = 0; a < 4; ++a)
#pragma unroll
        for (int e = 0; e < 4; ++e) acc[a][e] += qr[a] * kvr[e];
    }
#pragma unroll
    for (int a = 0; a < 4; ++a) {
      const int l = l0 + rr0 + a;
      const float sc = si[obase + l] * sa[obase + l];
      bf16x4 o;
#pragma unroll
      for (int e = 0; e < 4; ++e) o[e] = (__bf16)(acc[a][e] * sc);
      *(bf16x4*)&Xb[(bL + l) * Dc + h * 64 + mq] = o;
    }
  }
}

// ---------------- host ----------------
extern "C" void kernel_launch(void* const* d_in, const int* in_sizes, int n_in,
                              void* d_out, int out_size, void* d_ws, size_t ws_size,
                              hipStream_t stream) {
  const float* Qin = (const float*)d_in[0];
  const float* Kin = (const float*)d_in[1];
  const float* Vin = (const float*)d_in[2];
  const float* Wq = (const float*)d_in[3];
  const float* bq = (const float*)d_in[4];
  const float* Wk = (const float*)d_in[5];
  const float* bk = (const float*)d_in[6];
  const float* Wv = (const float*)d_in[7];
  const float* bv = (const float*)d_in[8];
  const float* Wo = (const float*)d_in[9];
  const float* bo = (const float*)d_in[10];

  const size_t MD = (size_t)Mc * Dc;
  __bf16* Aq = (__bf16*)d_ws;
  __bf16* Ak = Aq + MD;
  __bf16* Av = Ak + MD;
  __bf16* Wqt = Av + MD;
  __bf16* Wkt = Wqt + (size_t)Dc * Dc;
  __bf16* Wvt = Wkt + (size_t)Dc * Dc;
  __bf16* Wot = Wvt + (size_t)Dc * Dc;
  __bf16* QKV = Wot + (size_t)Dc * Dc;          // [M][3072]
  float* F = (float*)(QKV + (size_t)Mc * LDQ);
  float* ksum = F;              // 4096
  float* qsum = ksum + 4096;    // 4096
  float* kso = qsum + 4096;     // 4096
  float* qsi = kso + 4096;      // 4096
  float* den = qsi + 4096;      // 64
  float* kv = den + 64;         // 64*4096
  float* si = kv + 262144;
  float* sa = si + 262144;
  float* csx = sa + 262144;
  __bf16* Xb = Aq;              // reuse Aq (dead after QKV GEMM)

  hipMemsetAsync(F, 0, (size_t)(4 * 4096 + 64 + 262144) * sizeof(float), stream);

  conv3<<<dim3((int)(MD / 4 / 256), 3), 256, 0, stream>>>(Qin, Kin, Vin, Aq);
  wt_conv4<<<dim3(32, 32, 4), dim3(32, 8), 0, stream>>>(Wq, Wk, Wv, Wo, Wqt);

  // fused grouped QKV projection: one dispatch, 3072 blocks of 128x128
  gemm128<1><<<dim3(128, 24), 256, 0, stream>>>(Aq, Ak, Av, Wqt, Wkt, Wvt,
                                                bq, bk, bv, QKV, qsum, ksum);

  const __bf16* Qp = QKV;
  const __bf16* Kp = QKV + 1024;
  const __bf16* Vp = QKV + 2048;
  r2_flow<<<1024, 256, 0, stream>>>(Qp, Kp, ksum, qsum, si, qsi, kso);
  r3_cons<<<1024, 256, 0, stream>>>(Qp, Kp, qsi, kso, sa, csx, den);
  k5_kv<<<dim3(64, 8), 256, 0, stream>>>(Kp, Vp, csx, den, kv);
  k6_x<<<dim3(64, 16), 256, 0, stream>>>(Qp, kv, si, sa, Xb);

  // output projection: fp32 out, 1024 blocks of 128x128
  gemm128<0><<<dim3(128, 8), 256, 0, stream>>>(Xb, nullptr, nullptr, Wot, nullptr, nullptr,
                                               bo, nullptr, nullptr, d_out, nullptr, nullptr);
}

// Round 11
// 497.280 us; speedup vs baseline: 1.0762x; 1.0508x over previous
//
#include <hip/hip_runtime.h>

#define Bc 4
#define Lc 4096
#define Dc 1024
#define LDQ 3072
#define Mc (Bc*Lc)
#define EPSc 1e-6f

typedef __bf16 bf16x8 __attribute__((ext_vector_type(8)));
typedef __bf16 bf16x4 __attribute__((ext_vector_type(4)));
typedef float f32x4 __attribute__((ext_vector_type(4)));

typedef __attribute__((address_space(3))) void lds_vt;
typedef const __attribute__((address_space(1))) void gbl_vt;

__device__ __forceinline__ void gll16(const void* g, void* l) {
  __builtin_amdgcn_global_load_lds((gbl_vt*)g, (lds_vt*)l, 16, 0, 0);
}

// ---------------- fused converts (validated) ----------------
__global__ __launch_bounds__(256) void conv3(const float* __restrict__ Q, const float* __restrict__ K,
                                             const float* __restrict__ V, __bf16* __restrict__ Y) {
  const float* src = (blockIdx.y == 0) ? Q : (blockIdx.y == 1) ? K : V;
  __bf16* dst = Y + (size_t)blockIdx.y * ((size_t)Mc * Dc);
  const int i = blockIdx.x * 256 + threadIdx.x;
  const float4 v = ((const float4*)src)[i];
  bf16x4 o;
  o[0] = (__bf16)v.x; o[1] = (__bf16)v.y; o[2] = (__bf16)v.z; o[3] = (__bf16)v.w;
  ((bf16x4*)dst)[i] = o;
}

__global__ __launch_bounds__(256) void wt_conv4(const float* __restrict__ W0, const float* __restrict__ W1,
                                                const float* __restrict__ W2, const float* __restrict__ W3,
                                                __bf16* __restrict__ T) {
  const float* W = (blockIdx.z == 0) ? W0 : (blockIdx.z == 1) ? W1 : (blockIdx.z == 2) ? W2 : W3;
  __bf16* Wt = T + (size_t)blockIdx.z * ((size_t)Dc * Dc);
  __shared__ float t[32][33];
  const int n0 = blockIdx.x << 5, k0 = blockIdx.y << 5;
  const int tx = threadIdx.x, ty = threadIdx.y;  // block (32,8)
#pragma unroll
  for (int i = 0; i < 4; ++i)
    t[ty + 8 * i][tx] = W[(size_t)(k0 + ty + 8 * i) * Dc + n0 + tx];
  __syncthreads();
#pragma unroll
  for (int i = 0; i < 4; ++i)
    Wt[(size_t)(n0 + ty + 8 * i) * Dc + k0 + tx] = (__bf16)t[tx][ty + 8 * i];
}

// ---------------- GEMM 128x128, BK=32, single-buffer LDS (r7/r10-validated) ----------------
template <int FUSED>
__global__ __launch_bounds__(256, 4) void gemm128(
    const __bf16* __restrict__ Aq_, const __bf16* __restrict__ Ak_, const __bf16* __restrict__ Av_,
    const __bf16* __restrict__ Wq_, const __bf16* __restrict__ Wk_, const __bf16* __restrict__ Wv_,
    const float* __restrict__ bq_, const float* __restrict__ bk_, const float* __restrict__ bv_,
    void* __restrict__ Cp, float* __restrict__ qsum, float* __restrict__ ksum) {
  __shared__ __bf16 As[128 * 32];
  __shared__ __bf16 Bs[128 * 32];
  const int tid = threadIdx.x;
  const int lane = tid & 63, w4 = tid >> 6;
  const int wr = w4 >> 1, wc = w4 & 1;          // 2 x 2 waves, 64x64 each
  const int lf = lane & 15, kq = lane >> 4;

  constexpr int NCT = FUSED ? 24 : 8;
  constexpr int CPX = (128 * NCT) >> 3;
  const int hwlin = blockIdx.x + (blockIdx.y << 7);
  const int swz = (hwlin & 7) * CPX + (hwlin >> 3);
  const int bx = swz / NCT, ct = swz - bx * NCT;
  const int row0 = bx << 7, col0 = ct << 7;
  const int region = FUSED ? (ct >> 3) : 0;
  const int colL = FUSED ? (col0 & 1023) : col0;

  const __bf16* Agl = FUSED ? (region == 0 ? Aq_ : (region == 1 ? Ak_ : Av_)) : Aq_;
  const __bf16* Bgl = FUSED ? (region == 0 ? Wq_ : (region == 1 ? Wk_ : Wv_)) : Wq_;
  const float* biasp = FUSED ? (region == 0 ? bq_ : (region == 1 ? bk_ : bv_)) : bq_;
  const __bf16* Ab_g = Agl + (size_t)row0 * 1024;
  const __bf16* Bb_g = Bgl + (size_t)colL * 1024;

  const int srow = (w4 << 5) + (lane >> 2);
  const int sgd = lane & 3;
  const int ssrc = (sgd ^ ((lane >> 3) & 3)) << 3;
  const size_t aoff0 = (size_t)srow * 1024 + ssrc;
  const size_t aoff1 = (size_t)(srow + 16) * 1024 + ssrc;
  const int ldst0 = srow * 32 + (sgd << 3);
  const int ldst1 = (srow + 16) * 32 + (sgd << 3);

  const int kgsw = (kq ^ ((lf >> 1) & 3)) << 3;
  const int arb = (wr * 64 + lf) * 32 + kgsw;
  const int brb = (wc * 64 + lf) * 32 + kgsw;

  f32x4 acc[4][4] = {};

  for (int t = 0; t < 32; ++t) {
    const int kb = t << 5;
    gll16(Ab_g + aoff0 + kb, &As[ldst0]);
    gll16(Ab_g + aoff1 + kb, &As[ldst1]);
    gll16(Bb_g + aoff0 + kb, &Bs[ldst0]);
    gll16(Bb_g + aoff1 + kb, &Bs[ldst1]);
    __syncthreads();
    bf16x8 af[4], bfr[4];
#pragma unroll
    for (int m = 0; m < 4; ++m) af[m] = *(const bf16x8*)(As + arb + m * 512);
#pragma unroll
    for (int n = 0; n < 4; ++n) bfr[n] = *(const bf16x8*)(Bs + brb + n * 512);
#pragma unroll
    for (int m = 0; m < 4; ++m)
#pragma unroll
      for (int n = 0; n < 4; ++n)
        acc[m][n] = __builtin_amdgcn_mfma_f32_16x16x32_bf16(bfr[n], af[m], acc[m][n], 0, 0, 0);
    __syncthreads();
  }

  const int b_of = row0 >> 12;
  const int orow = row0 + wr * 64 + lf;
  const int ocl = wc * 64 + (kq << 2);
#pragma unroll
  for (int n = 0; n < 4; ++n) {
    const int cl = ocl + (n << 4);
    const int cb = colL + cl;
    const f32x4 bb = *(const f32x4*)&biasp[cb];
    f32x4 sacc = {0.f, 0.f, 0.f, 0.f};
#pragma unroll
    for (int m = 0; m < 4; ++m) {
      f32x4 v = acc[m][n] + bb;
      if (FUSED && region < 2) {
#pragma unroll
        for (int r = 0; r < 4; ++r) v[r] = 1.0f / (1.0f + expf(-v[r]));
      }
      if (FUSED) {
        bf16x4 o;
#pragma unroll
        for (int r = 0; r < 4; ++r) o[r] = (__bf16)v[r];
        *(bf16x4*)&((__bf16*)Cp)[(size_t)(orow + (m << 4)) * LDQ + col0 + cl] = o;
      } else {
        *(f32x4*)&((float*)Cp)[(size_t)(orow + (m << 4)) * 1024 + col0 + cl] = v;
      }
      sacc += v;
    }
    if (FUSED && region < 2) {
#pragma unroll
      for (int o = 1; o < 16; o <<= 1) {
        sacc[0] += __shfl_xor(sacc[0], o); sacc[1] += __shfl_xor(sacc[1], o);
        sacc[2] += __shfl_xor(sacc[2], o); sacc[3] += __shfl_xor(sacc[3], o);
      }
      if (lf == 0) {
        float* sums = (region == 0) ? qsum : ksum;
#pragma unroll
        for (int r = 0; r < 4; ++r) atomicAdd(&sums[b_of * 1024 + cb + r], sacc[r]);
      }
    }
  }
}

// ---------------- r2: si + qsi/kso (r7/r10-validated) ----------------
__global__ __launch_bounds__(256) void r2_flow(const __bf16* __restrict__ Qp, const __bf16* __restrict__ Kp,
                                               const float* __restrict__ ksum, const float* __restrict__ qsum,
                                               float* __restrict__ si,
                                               float* __restrict__ qsi, float* __restrict__ kso) {
  const int blk = blockIdx.x;
  const int chunk = blk & 15, bh = blk >> 4;
  const int b = bh >> 4, h = bh & 15;
  const int d = threadIdx.x & 63, w = threadIdx.x >> 6;
  __shared__ float ksE[64], qsE[64];
  if (threadIdx.x < 64) ksE[threadIdx.x] = ksum[bh * 64 + threadIdx.x] + EPSc;
  else if (threadIdx.x < 128) qsE[threadIdx.x - 64] = qsum[bh * 64 + threadIdx.x - 64] + EPSc;
  __syncthreads();
  const float kE = ksE[d], qE = qsE[d];
  const size_t base = ((size_t)b * Lc) * LDQ + h * 64 + d;
  const size_t obase = (size_t)bh * Lc;
  float qsia = 0.f, ksoa = 0.f;
  const int l0 = chunk * 256;
  for (int i = w; i < 256; i += 4) {
    const int l = l0 + i;
    const size_t idx = base + (size_t)l * LDQ;
    const float qv = (float)Qp[idx], kvv = (float)Kp[idx];
    float a = (qv + EPSc) * kE;
    float c2 = (kvv + EPSc) * qE;
#pragma unroll
    for (int o = 32; o; o >>= 1) { a += __shfl_xor(a, o); c2 += __shfl_xor(c2, o); }
    const float sil = 1.0f / a, sol = 1.0f / c2;
    if (d == 0) si[obase + l] = sil;
    qsia += qv * sil;
    ksoa += kvv * sol;
  }
  atomicAdd(&qsi[bh * 64 + d], qsia);
  atomicAdd(&kso[bh * 64 + d], ksoa);
}

// ---------------- r3: sa + csx + den (r7/r10-validated) ----------------
__global__ __launch_bounds__(256) void r3_cons(const __bf16* __restrict__ Qp, const __bf16* __restrict__ Kp,
                                               const float* __restrict__ qsi, const float* __restrict__ kso,
                                               float* __restrict__ sa, float* __restrict__ csx,
                                               float* __restrict__ den) {
  const int blk = blockIdx.x;
  const int chunk = blk & 15, bh = blk >> 4;
  const int b = bh >> 4, h = bh & 15;
  const int d = threadIdx.x & 63, w = threadIdx.x >> 6;
  __shared__ float ksoE[64], qsiE[64];
  if (threadIdx.x < 64) ksoE[threadIdx.x] = kso[bh * 64 + threadIdx.x] + EPSc;
  else if (threadIdx.x < 128) qsiE[threadIdx.x - 64] = qsi[bh * 64 + threadIdx.x - 64] + EPSc;
  __syncthreads();
  const float kE = ksoE[d], qE = qsiE[d];
  const size_t base = ((size_t)b * Lc) * LDQ + h * 64 + d;
  const size_t obase = (size_t)bh * Lc;
  const int l0 = chunk * 256;
  float eacc = 0.f;
  for (int i = w; i < 256; i += 4) {
    const int l = l0 + i;
    const size_t idx = base + (size_t)l * LDQ;
    const float qv = (float)Qp[idx], kvv = (float)Kp[idx];
    float a = (qv + EPSc) * kE;
    float c2 = (kvv + EPSc) * qE;
#pragma unroll
    for (int o = 32; o; o >>= 1) { a += __shfl_xor(a, o); c2 += __shfl_xor(c2, o); }
    if (d == 0) {
      sa[obase + l] = 1.0f / (1.0f + expf(-a));
      const float cl = fminf(1.0f, fmaxf(-1.0f, c2));
      const float e = expf(cl);          // max-free softmax: cl in [-1,1]
      csx[obase + l] = e;
      eacc += e;
    }
  }
  if (d == 0) atomicAdd(&den[bh], eacc);
}

// ---------------- k5: kv[d][m] = sum_l k * (v * scomp)  (r7/r10-validated) ----------------
__global__ __launch_bounds__(256) void k5_kv(const __bf16* __restrict__ Kp, const __bf16* __restrict__ Vp,
                                             const float* __restrict__ csx, const float* __restrict__ den,
                                             float* __restrict__ kvout) {
  const int bh = blockIdx.x, chunk = blockIdx.y;  // chunk of 512 rows
  const int b = bh >> 4, h = bh & 15;
  const int tid = threadIdx.x;
  const int dq = (tid >> 4) << 2;
  const int mq = (tid & 15) << 2;
  const float sden = 4096.0f / den[bh];
  __shared__ float klds[4][64], vlds[4][64];
  float acc[4][4] = {};
  const int r = tid >> 6, c = tid & 63;
  const size_t rowbase = ((size_t)b * Lc + chunk * 512) * LDQ + h * 64;
  const size_t csbase = (size_t)bh * Lc + chunk * 512;
  for (int i = 0; i < 512; i += 4) {
    const size_t idx = rowbase + (size_t)(i + r) * LDQ + c;
    const float sc = csx[csbase + i + r] * sden;
    klds[r][c] = (float)Kp[idx];
    vlds[r][c] = (float)Vp[idx] * sc;
    __syncthreads();
#pragma unroll
    for (int rr = 0; rr < 4; ++rr) {
      float kr[4], vr[4];
#pragma unroll
      for (int j = 0; j < 4; ++j) { kr[j] = klds[rr][dq + j]; vr[j] = vlds[rr][mq + j]; }
#pragma unroll
      for (int a = 0; a < 4; ++a)
#pragma unroll
        for (int e = 0; e < 4; ++e) acc[a][e] += kr[a] * vr[e];
    }
    __syncthreads();
  }
#pragma unroll
  for (int a = 0; a < 4; ++a)
#pragma unroll
    for (int e = 0; e < 4; ++e)
      atomicAdd(&kvout[(size_t)bh * 4096 + (dq + a) * 64 + mq + e], acc[a][e]);
}

// ---------------- k6: x = (q @ kv) * si * sa via MFMA (hi/lo-split kv) ----------------
// kv[d][m] (normalized, from validated k5) is transposed once into LDS ktl[m][d];
// A-operand (output cols) = kv rows m, B... operands follow the gemm128-validated
// convention: mfma(colsOp, rowsOp, acc) -> C[row from rowsOp(lf)][col = kq*4+r].
__global__ __launch_bounds__(256) void k6_x(const __bf16* __restrict__ Qp,
                                            const float* __restrict__ kvin, const float* __restrict__ si,
                                            const float* __restrict__ sa, __bf16* __restrict__ Xb) {
  const int bh = blockIdx.x, chunk = blockIdx.y;  // chunk of 256 rows
  const int b = bh >> 4, h = bh & 15;
  const int tid = threadIdx.x, lane = tid & 63, w = tid >> 6;
  const int lf = lane & 15, kq = lane >> 4;
  __shared__ float ktl[64][66];                  // ktl[m][d]
  for (int e = tid; e < 4096; e += 256)          // e = d*64 + m
    ktl[e & 63][e >> 6] = kvin[(size_t)bh * 4096 + e];
  __syncthreads();
  // hoist kv fragments, hi+lo bf16 split (combined rel. precision ~2^-17)
  bf16x8 kh[4][2], kl[4][2];
#pragma unroll
  for (int mi = 0; mi < 4; ++mi)
#pragma unroll
    for (int hf = 0; hf < 2; ++hf) {
      const float* p = &ktl[mi * 16 + lf][hf * 32 + kq * 8];
      bf16x8 hi, lo;
#pragma unroll
      for (int j = 0; j < 8; ++j) {
        const float f = p[j];
        hi[j] = (__bf16)f;
        lo[j] = (__bf16)(f - (float)hi[j]);
      }
      kh[mi][hf] = hi; kl[mi][hf] = lo;
    }
  const size_t bL = (size_t)b * Lc;
  const size_t obase = (size_t)bh * Lc;
#pragma unroll
  for (int gi = 0; gi < 4; ++gi) {
    const int lrow = chunk * 256 + (w * 4 + gi) * 16 + lf;
    const size_t qb = (bL + lrow) * LDQ + h * 64;
    const bf16x8 qf0 = *(const bf16x8*)(Qp + qb + kq * 8);
    const bf16x8 qf1 = *(const bf16x8*)(Qp + qb + 32 + kq * 8);
    const float sc = si[obase + lrow] * sa[obase + lrow];
    f32x4 acc[4] = {};
#pragma unroll
    for (int mi = 0; mi < 4; ++mi) {
      acc[mi] = __builtin_amdgcn_mfma_f32_16x16x32_bf16(kh[mi][0], qf0, acc[mi], 0, 0, 0);
      acc[mi] = __builtin_amdgcn_mfma_f32_16x16x32_bf16(kh[mi][1], qf1, acc[mi], 0, 0, 0);
      acc[mi] = __builtin_amdgcn_mfma_f32_16x16x32_bf16(kl[mi][0], qf0, acc[mi], 0, 0, 0);
      acc[mi] = __builtin_amdgcn_mfma_f32_16x16x32_bf16(kl[mi][1], qf1, acc[mi], 0, 0, 0);
    }
#pragma unroll
    for (int mi = 0; mi < 4; ++mi) {
      bf16x4 o;
#pragma unroll
      for (int r = 0; r < 4; ++r) o[r] = (__bf16)(acc[mi][r] * sc);
      *(bf16x4*)&Xb[(bL + lrow) * Dc + h * 64 + mi * 16 + (kq << 2)] = o;
    }
  }
}

// ---------------- host ----------------
extern "C" void kernel_launch(void* const* d_in, const int* in_sizes, int n_in,
                              void* d_out, int out_size, void* d_ws, size_t ws_size,
                              hipStream_t stream) {
  const float* Qin = (const float*)d_in[0];
  const float* Kin = (const float*)d_in[1];
  const float* Vin = (const float*)d_in[2];
  const float* Wq = (const float*)d_in[3];
  const float* bq = (const float*)d_in[4];
  const float* Wk = (const float*)d_in[5];
  const float* bk = (const float*)d_in[6];
  const float* Wv = (const float*)d_in[7];
  const float* bv = (const float*)d_in[8];
  const float* Wo = (const float*)d_in[9];
  const float* bo = (const float*)d_in[10];

  const size_t MD = (size_t)Mc * Dc;
  __bf16* Aq = (__bf16*)d_ws;
  __bf16* Ak = Aq + MD;
  __bf16* Av = Ak + MD;
  __bf16* Wqt = Av + MD;
  __bf16* Wkt = Wqt + (size_t)Dc * Dc;
  __bf16* Wvt = Wkt + (size_t)Dc * Dc;
  __bf16* Wot = Wvt + (size_t)Dc * Dc;
  __bf16* QKV = Wot + (size_t)Dc * Dc;          // [M][3072]
  float* F = (float*)(QKV + (size_t)Mc * LDQ);
  float* ksum = F;              // 4096
  float* qsum = ksum + 4096;    // 4096
  float* kso = qsum + 4096;     // 4096
  float* qsi = kso + 4096;      // 4096
  float* den = qsi + 4096;      // 64
  float* kv = den + 64;         // 64*4096
  float* si = kv + 262144;
  float* sa = si + 262144;
  float* csx = sa + 262144;
  __bf16* Xb = Aq;              // reuse Aq (dead after QKV GEMM)

  hipMemsetAsync(F, 0, (size_t)(4 * 4096 + 64 + 262144) * sizeof(float), stream);

  conv3<<<dim3((int)(MD / 4 / 256), 3), 256, 0, stream>>>(Qin, Kin, Vin, Aq);
  wt_conv4<<<dim3(32, 32, 4), dim3(32, 8), 0, stream>>>(Wq, Wk, Wv, Wo, Wqt);

  // fused grouped QKV projection: one dispatch, 3072 blocks of 128x128
  gemm128<1><<<dim3(128, 24), 256, 0, stream>>>(Aq, Ak, Av, Wqt, Wkt, Wvt,
                                                bq, bk, bv, QKV, qsum, ksum);

  const __bf16* Qp = QKV;
  const __bf16* Kp = QKV + 1024;
  const __bf16* Vp = QKV + 2048;
  r2_flow<<<1024, 256, 0, stream>>>(Qp, Kp, ksum, qsum, si, qsi, kso);
  r3_cons<<<1024, 256, 0, stream>>>(Qp, Kp, qsi, kso, sa, csx, den);
  k5_kv<<<dim3(64, 8), 256, 0, stream>>>(Kp, Vp, csx, den, kv);
  k6_x<<<dim3(64, 16), 256, 0, stream>>>(Qp, kv, si, sa, Xb);

  // output projection: fp32 out, 1024 blocks of 128x128
  gemm128<0><<<dim3(128, 8), 256, 0, stream>>>(Xb, nullptr, nullptr, Wot, nullptr, nullptr,
                                               bo, nullptr, nullptr, d_out, nullptr, nullptr);
}

// Round 12
// 490.640 us; speedup vs baseline: 1.0908x; 1.0135x over previous
//
#include <hip/hip_runtime.h>

#define Bc 4
#define Lc 4096
#define Dc 1024
#define LDQ 3072
#define Mc (Bc*Lc)
#define EPSc 1e-6f

typedef __bf16 bf16x8 __attribute__((ext_vector_type(8)));
typedef __bf16 bf16x4 __attribute__((ext_vector_type(4)));
typedef float f32x4 __attribute__((ext_vector_type(4)));

typedef __attribute__((address_space(3))) void lds_vt;
typedef const __attribute__((address_space(1))) void gbl_vt;

__device__ __forceinline__ void gll16(const void* g, void* l) {
  __builtin_amdgcn_global_load_lds((gbl_vt*)g, (lds_vt*)l, 16, 0, 0);
}

// ---------------- fused converts (validated) ----------------
__global__ __launch_bounds__(256) void conv3(const float* __restrict__ Q, const float* __restrict__ K,
                                             const float* __restrict__ V, __bf16* __restrict__ Y) {
  const float* src = (blockIdx.y == 0) ? Q : (blockIdx.y == 1) ? K : V;
  __bf16* dst = Y + (size_t)blockIdx.y * ((size_t)Mc * Dc);
  const int i = blockIdx.x * 256 + threadIdx.x;
  const float4 v = ((const float4*)src)[i];
  bf16x4 o;
  o[0] = (__bf16)v.x; o[1] = (__bf16)v.y; o[2] = (__bf16)v.z; o[3] = (__bf16)v.w;
  ((bf16x4*)dst)[i] = o;
}

__global__ __launch_bounds__(256) void wt_conv4(const float* __restrict__ W0, const float* __restrict__ W1,
                                                const float* __restrict__ W2, const float* __restrict__ W3,
                                                __bf16* __restrict__ T) {
  const float* W = (blockIdx.z == 0) ? W0 : (blockIdx.z == 1) ? W1 : (blockIdx.z == 2) ? W2 : W3;
  __bf16* Wt = T + (size_t)blockIdx.z * ((size_t)Dc * Dc);
  __shared__ float t[32][33];
  const int n0 = blockIdx.x << 5, k0 = blockIdx.y << 5;
  const int tx = threadIdx.x, ty = threadIdx.y;  // block (32,8)
#pragma unroll
  for (int i = 0; i < 4; ++i)
    t[ty + 8 * i][tx] = W[(size_t)(k0 + ty + 8 * i) * Dc + n0 + tx];
  __syncthreads();
#pragma unroll
  for (int i = 0; i < 4; ++i)
    Wt[(size_t)(n0 + ty + 8 * i) * Dc + k0 + tx] = (__bf16)t[tx][ty + 8 * i];
}

// ---------------- GEMM 256x128 block, BK=32, single-buffer LDS, 128x64 per wave ----------
// Same validated staging/swizzle/read/epilogue conventions as r7-r11 gemm128; the only
// structural change: block = 256 rows x 128 cols, 4 waves (wr in {0,1} x wc in {0,1}),
// each wave owns 128x64 (8 m-frags x 4 n-frags) -> LDS bytes/MFMA 512 -> 384.
// FUSED=1: grouped QKV projection (sigmoid Q,K; col-sum atomics; bf16 out ld=3072).
// FUSED=0: plain C = A@Wt^T + bias, fp32 out ld=1024.
template <int FUSED>
__global__ __launch_bounds__(256, 2) void gemm256x128(
    const __bf16* __restrict__ Aq_, const __bf16* __restrict__ Ak_, const __bf16* __restrict__ Av_,
    const __bf16* __restrict__ Wq_, const __bf16* __restrict__ Wk_, const __bf16* __restrict__ Wv_,
    const float* __restrict__ bq_, const float* __restrict__ bk_, const float* __restrict__ bv_,
    void* __restrict__ Cp, float* __restrict__ qsum, float* __restrict__ ksum) {
  __shared__ __bf16 As[256 * 32];
  __shared__ __bf16 Bs[128 * 32];
  const int tid = threadIdx.x;
  const int lane = tid & 63, w4 = tid >> 6;
  const int wr = w4 >> 1, wc = w4 & 1;          // 2 x 2 waves; wave tile 128 x 64
  const int lf = lane & 15, kq = lane >> 4;

  // XCD-chunked bijective swizzle, cols fastest (A-panel L2 reuse per XCD)
  constexpr int NCT = FUSED ? 24 : 8;           // 128-col tiles
  constexpr int CPX = (64 * NCT) >> 3;
  const int hwlin = blockIdx.x + blockIdx.y * 64;
  const int swz = (hwlin & 7) * CPX + (hwlin >> 3);
  const int bx = swz / NCT, ct = swz - bx * NCT;
  const int row0 = bx << 8, col0 = ct << 7;
  const int region = FUSED ? (ct >> 3) : 0;
  const int colL = FUSED ? (col0 & 1023) : col0;

  const __bf16* Agl = FUSED ? (region == 0 ? Aq_ : (region == 1 ? Ak_ : Av_)) : Aq_;
  const __bf16* Bgl = FUSED ? (region == 0 ? Wq_ : (region == 1 ? Wk_ : Wv_)) : Wq_;
  const float* biasp = FUSED ? (region == 0 ? bq_ : (region == 1 ? bk_ : bv_)) : bq_;
  const __bf16* Ab_g = Agl + (size_t)row0 * 1024;
  const __bf16* Bb_g = Bgl + (size_t)colL * 1024;

  // staging constants (t-invariant): granule g -> row=g>>2, dst granule gd=g&3,
  // src k-granule = gd ^ ((row>>1)&3); dst elem = g*8 (wave-uniform + lane*16B)
  int arow[4], asrc[4];
#pragma unroll
  for (int i = 0; i < 4; ++i) {
    const int g = i * 256 + tid;
    arow[i] = g >> 2;
    asrc[i] = ((g & 3) ^ ((arow[i] >> 1) & 3)) << 3;
  }
  // frag read bases: same conflict-free pattern as validated gemm128
  const int kgsw = (kq ^ ((lf >> 1) & 3)) << 3;
  const int arb = (wr * 128 + lf) * 32 + kgsw;
  const int brb = (wc * 64 + lf) * 32 + kgsw;

  f32x4 acc[8][4] = {};

  for (int t = 0; t < 32; ++t) {
    const int kb = t << 5;
#pragma unroll
    for (int i = 0; i < 4; ++i)
      gll16(Ab_g + (size_t)arow[i] * 1024 + kb + asrc[i], &As[(i * 256 + tid) * 8]);
#pragma unroll
    for (int i = 0; i < 2; ++i)
      gll16(Bb_g + (size_t)arow[i] * 1024 + kb + asrc[i], &Bs[(i * 256 + tid) * 8]);
    __syncthreads();
    bf16x8 af[8], bfr[4];
#pragma unroll
    for (int m = 0; m < 8; ++m) af[m] = *(const bf16x8*)(As + arb + m * 512);
#pragma unroll
    for (int n = 0; n < 4; ++n) bfr[n] = *(const bf16x8*)(Bs + brb + n * 512);
#pragma unroll
    for (int m = 0; m < 8; ++m)
#pragma unroll
      for (int n = 0; n < 4; ++n)
        acc[m][n] = __builtin_amdgcn_mfma_f32_16x16x32_bf16(bfr[n], af[m], acc[m][n], 0, 0, 0);
    __syncthreads();
  }

  // epilogue: acc[m][n][r] = C[row0 + wr*128 + m*16 + lf][col0 + wc*64 + n*16 + kq*4 + r]
  const int b_of = row0 >> 12;
  const int orow = row0 + wr * 128 + lf;
  const int ocl = wc * 64 + (kq << 2);
#pragma unroll
  for (int n = 0; n < 4; ++n) {
    const int cl = ocl + (n << 4);           // 0..127 within tile
    const int cb = colL + cl;                // bias/sum col (0..1023)
    const f32x4 bb = *(const f32x4*)&biasp[cb];
    f32x4 sacc = {0.f, 0.f, 0.f, 0.f};
#pragma unroll
    for (int m = 0; m < 8; ++m) {
      f32x4 v = acc[m][n] + bb;
      if (FUSED && region < 2) {
#pragma unroll
        for (int r = 0; r < 4; ++r) v[r] = 1.0f / (1.0f + expf(-v[r]));
      }
      if (FUSED) {
        bf16x4 o;
#pragma unroll
        for (int r = 0; r < 4; ++r) o[r] = (__bf16)v[r];
        *(bf16x4*)&((__bf16*)Cp)[(size_t)(orow + (m << 4)) * LDQ + col0 + cl] = o;
      } else {
        *(f32x4*)&((float*)Cp)[(size_t)(orow + (m << 4)) * 1024 + col0 + cl] = v;
      }
      sacc += v;
    }
    if (FUSED && region < 2) {
#pragma unroll
      for (int o = 1; o < 16; o <<= 1) {
        sacc[0] += __shfl_xor(sacc[0], o); sacc[1] += __shfl_xor(sacc[1], o);
        sacc[2] += __shfl_xor(sacc[2], o); sacc[3] += __shfl_xor(sacc[3], o);
      }
      if (lf == 0) {
        float* sums = (region == 0) ? qsum : ksum;
#pragma unroll
        for (int r = 0; r < 4; ++r) atomicAdd(&sums[b_of * 1024 + cb + r], sacc[r]);
      }
    }
  }
}

// ---------------- r2: si + qsi/kso (r7/r10-validated) ----------------
__global__ __launch_bounds__(256) void r2_flow(const __bf16* __restrict__ Qp, const __bf16* __restrict__ Kp,
                                               const float* __restrict__ ksum, const float* __restrict__ qsum,
                                               float* __restrict__ si,
                                               float* __restrict__ qsi, float* __restrict__ kso) {
  const int blk = blockIdx.x;
  const int chunk = blk & 15, bh = blk >> 4;
  const int b = bh >> 4, h = bh & 15;
  const int d = threadIdx.x & 63, w = threadIdx.x >> 6;
  __shared__ float ksE[64], qsE[64];
  if (threadIdx.x < 64) ksE[threadIdx.x] = ksum[bh * 64 + threadIdx.x] + EPSc;
  else if (threadIdx.x < 128) qsE[threadIdx.x - 64] = qsum[bh * 64 + threadIdx.x - 64] + EPSc;
  __syncthreads();
  const float kE = ksE[d], qE = qsE[d];
  const size_t base = ((size_t)b * Lc) * LDQ + h * 64 + d;
  const size_t obase = (size_t)bh * Lc;
  float qsia = 0.f, ksoa = 0.f;
  const int l0 = chunk * 256;
  for (int i = w; i < 256; i += 4) {
    const int l = l0 + i;
    const size_t idx = base + (size_t)l * LDQ;
    const float qv = (float)Qp[idx], kvv = (float)Kp[idx];
    float a = (qv + EPSc) * kE;
    float c2 = (kvv + EPSc) * qE;
#pragma unroll
    for (int o = 32; o; o >>= 1) { a += __shfl_xor(a, o); c2 += __shfl_xor(c2, o); }
    const float sil = 1.0f / a, sol = 1.0f / c2;
    if (d == 0) si[obase + l] = sil;
    qsia += qv * sil;
    ksoa += kvv * sol;
  }
  atomicAdd(&qsi[bh * 64 + d], qsia);
  atomicAdd(&kso[bh * 64 + d], ksoa);
}

// ---------------- r3: sa + csx + den (r7/r10-validated) ----------------
__global__ __launch_bounds__(256) void r3_cons(const __bf16* __restrict__ Qp, const __bf16* __restrict__ Kp,
                                               const float* __restrict__ qsi, const float* __restrict__ kso,
                                               float* __restrict__ sa, float* __restrict__ csx,
                                               float* __restrict__ den) {
  const int blk = blockIdx.x;
  const int chunk = blk & 15, bh = blk >> 4;
  const int b = bh >> 4, h = bh & 15;
  const int d = threadIdx.x & 63, w = threadIdx.x >> 6;
  __shared__ float ksoE[64], qsiE[64];
  if (threadIdx.x < 64) ksoE[threadIdx.x] = kso[bh * 64 + threadIdx.x] + EPSc;
  else if (threadIdx.x < 128) qsiE[threadIdx.x - 64] = qsi[bh * 64 + threadIdx.x - 64] + EPSc;
  __syncthreads();
  const float kE = ksoE[d], qE = qsiE[d];
  const size_t base = ((size_t)b * Lc) * LDQ + h * 64 + d;
  const size_t obase = (size_t)bh * Lc;
  const int l0 = chunk * 256;
  float eacc = 0.f;
  for (int i = w; i < 256; i += 4) {
    const int l = l0 + i;
    const size_t idx = base + (size_t)l * LDQ;
    const float qv = (float)Qp[idx], kvv = (float)Kp[idx];
    float a = (qv + EPSc) * kE;
    float c2 = (kvv + EPSc) * qE;
#pragma unroll
    for (int o = 32; o; o >>= 1) { a += __shfl_xor(a, o); c2 += __shfl_xor(c2, o); }
    if (d == 0) {
      sa[obase + l] = 1.0f / (1.0f + expf(-a));
      const float cl = fminf(1.0f, fmaxf(-1.0f, c2));
      const float e = expf(cl);          // max-free softmax: cl in [-1,1]
      csx[obase + l] = e;
      eacc += e;
    }
  }
  if (d == 0) atomicAdd(&den[bh], eacc);
}

// ---------------- k5: kv[d][m] = sum_l k * (v * scomp)  (r7/r10-validated) ----------------
__global__ __launch_bounds__(256) void k5_kv(const __bf16* __restrict__ Kp, const __bf16* __restrict__ Vp,
                                             const float* __restrict__ csx, const float* __restrict__ den,
                                             float* __restrict__ kvout) {
  const int bh = blockIdx.x, chunk = blockIdx.y;  // chunk of 512 rows
  const int b = bh >> 4, h = bh & 15;
  const int tid = threadIdx.x;
  const int dq = (tid >> 4) << 2;
  const int mq = (tid & 15) << 2;
  const float sden = 4096.0f / den[bh];
  __shared__ float klds[4][64], vlds[4][64];
  float acc[4][4] = {};
  const int r = tid >> 6, c = tid & 63;
  const size_t rowbase = ((size_t)b * Lc + chunk * 512) * LDQ + h * 64;
  const size_t csbase = (size_t)bh * Lc + chunk * 512;
  for (int i = 0; i < 512; i += 4) {
    const size_t idx = rowbase + (size_t)(i + r) * LDQ + c;
    const float sc = csx[csbase + i + r] * sden;
    klds[r][c] = (float)Kp[idx];
    vlds[r][c] = (float)Vp[idx] * sc;
    __syncthreads();
#pragma unroll
    for (int rr = 0; rr < 4; ++rr) {
      float kr[4], vr[4];
#pragma unroll
      for (int j = 0; j < 4; ++j) { kr[j] = klds[rr][dq + j]; vr[j] = vlds[rr][mq + j]; }
#pragma unroll
      for (int a = 0; a < 4; ++a)
#pragma unroll
        for (int e = 0; e < 4; ++e) acc[a][e] += kr[a] * vr[e];
    }
    __syncthreads();
  }
#pragma unroll
  for (int a = 0; a < 4; ++a)
#pragma unroll
    for (int e = 0; e < 4; ++e)
      atomicAdd(&kvout[(size_t)bh * 4096 + (dq + a) * 64 + mq + e], acc[a][e]);
}

// ---------------- k6: x = (q @ kv) * si * sa via MFMA (r11-validated) ----------------
__global__ __launch_bounds__(256) void k6_x(const __bf16* __restrict__ Qp,
                                            const float* __restrict__ kvin, const float* __restrict__ si,
                                            const float* __restrict__ sa, __bf16* __restrict__ Xb) {
  const int bh = blockIdx.x, chunk = blockIdx.y;  // chunk of 256 rows
  const int b = bh >> 4, h = bh & 15;
  const int tid = threadIdx.x, lane = tid & 63, w = tid >> 6;
  const int lf = lane & 15, kq = lane >> 4;
  __shared__ float ktl[64][66];                  // ktl[m][d]
  for (int e = tid; e < 4096; e += 256)          // e = d*64 + m
    ktl[e & 63][e >> 6] = kvin[(size_t)bh * 4096 + e];
  __syncthreads();
  bf16x8 kh[4][2], kl[4][2];
#pragma unroll
  for (int mi = 0; mi < 4; ++mi)
#pragma unroll
    for (int hf = 0; hf < 2; ++hf) {
      const float* p = &ktl[mi * 16 + lf][hf * 32 + kq * 8];
      bf16x8 hi, lo;
#pragma unroll
      for (int j = 0; j < 8; ++j) {
        const float f = p[j];
        hi[j] = (__bf16)f;
        lo[j] = (__bf16)(f - (float)hi[j]);
      }
      kh[mi][hf] = hi; kl[mi][hf] = lo;
    }
  const size_t bL = (size_t)b * Lc;
  const size_t obase = (size_t)bh * Lc;
#pragma unroll
  for (int gi = 0; gi < 4; ++gi) {
    const int lrow = chunk * 256 + (w * 4 + gi) * 16 + lf;
    const size_t qb = (bL + lrow) * LDQ + h * 64;
    const bf16x8 qf0 = *(const bf16x8*)(Qp + qb + kq * 8);
    const bf16x8 qf1 = *(const bf16x8*)(Qp + qb + 32 + kq * 8);
    const float sc = si[obase + lrow] * sa[obase + lrow];
    f32x4 acc[4] = {};
#pragma unroll
    for (int mi = 0; mi < 4; ++mi) {
      acc[mi] = __builtin_amdgcn_mfma_f32_16x16x32_bf16(kh[mi][0], qf0, acc[mi], 0, 0, 0);
      acc[mi] = __builtin_amdgcn_mfma_f32_16x16x32_bf16(kh[mi][1], qf1, acc[mi], 0, 0, 0);
      acc[mi] = __builtin_amdgcn_mfma_f32_16x16x32_bf16(kl[mi][0], qf0, acc[mi], 0, 0, 0);
      acc[mi] = __builtin_amdgcn_mfma_f32_16x16x32_bf16(kl[mi][1], qf1, acc[mi], 0, 0, 0);
    }
#pragma unroll
    for (int mi = 0; mi < 4; ++mi) {
      bf16x4 o;
#pragma unroll
      for (int r = 0; r < 4; ++r) o[r] = (__bf16)(acc[mi][r] * sc);
      *(bf16x4*)&Xb[(bL + lrow) * Dc + h * 64 + mi * 16 + (kq << 2)] = o;
    }
  }
}

// ---------------- host ----------------
extern "C" void kernel_launch(void* const* d_in, const int* in_sizes, int n_in,
                              void* d_out, int out_size, void* d_ws, size_t ws_size,
                              hipStream_t stream) {
  const float* Qin = (const float*)d_in[0];
  const float* Kin = (const float*)d_in[1];
  const float* Vin = (const float*)d_in[2];
  const float* Wq = (const float*)d_in[3];
  const float* bq = (const float*)d_in[4];
  const float* Wk = (const float*)d_in[5];
  const float* bk = (const float*)d_in[6];
  const float* Wv = (const float*)d_in[7];
  const float* bv = (const float*)d_in[8];
  const float* Wo = (const float*)d_in[9];
  const float* bo = (const float*)d_in[10];

  const size_t MD = (size_t)Mc * Dc;
  __bf16* Aq = (__bf16*)d_ws;
  __bf16* Ak = Aq + MD;
  __bf16* Av = Ak + MD;
  __bf16* Wqt = Av + MD;
  __bf16* Wkt = Wqt + (size_t)Dc * Dc;
  __bf16* Wvt = Wkt + (size_t)Dc * Dc;
  __bf16* Wot = Wvt + (size_t)Dc * Dc;
  __bf16* QKV = Wot + (size_t)Dc * Dc;          // [M][3072]
  float* F = (float*)(QKV + (size_t)Mc * LDQ);
  float* ksum = F;              // 4096
  float* qsum = ksum + 4096;    // 4096
  float* kso = qsum + 4096;     // 4096
  float* qsi = kso + 4096;      // 4096
  float* den = qsi + 4096;      // 64
  float* kv = den + 64;         // 64*4096
  float* si = kv + 262144;
  float* sa = si + 262144;
  float* csx = sa + 262144;
  __bf16* Xb = Aq;              // reuse Aq (dead after QKV GEMM)

  hipMemsetAsync(F, 0, (size_t)(4 * 4096 + 64 + 262144) * sizeof(float), stream);

  conv3<<<dim3((int)(MD / 4 / 256), 3), 256, 0, stream>>>(Qin, Kin, Vin, Aq);
  wt_conv4<<<dim3(32, 32, 4), dim3(32, 8), 0, stream>>>(Wq, Wk, Wv, Wo, Wqt);

  // fused grouped QKV projection: one dispatch, 1536 blocks of 256x128
  gemm256x128<1><<<dim3(64, 24), 256, 0, stream>>>(Aq, Ak, Av, Wqt, Wkt, Wvt,
                                                   bq, bk, bv, QKV, qsum, ksum);

  const __bf16* Qp = QKV;
  const __bf16* Kp = QKV + 1024;
  const __bf16* Vp = QKV + 2048;
  r2_flow<<<1024, 256, 0, stream>>>(Qp, Kp, ksum, qsum, si, qsi, kso);
  r3_cons<<<1024, 256, 0, stream>>>(Qp, Kp, qsi, kso, sa, csx, den);
  k5_kv<<<dim3(64, 8), 256, 0, stream>>>(Kp, Vp, csx, den, kv);
  k6_x<<<dim3(64, 16), 256, 0, stream>>>(Qp, kv, si, sa, Xb);

  // output projection: fp32 out, 512 blocks of 256x128
  gemm256x128<0><<<dim3(64, 8), 256, 0, stream>>>(Xb, nullptr, nullptr, Wot, nullptr, nullptr,
                                                  bo, nullptr, nullptr, d_out, nullptr, nullptr);
}